// Round 12
// baseline (806.652 us; speedup 1.0000x reference)
//
#include <hip/hip_runtime.h>
#include <hip/hip_bf16.h>

// Problem constants
constexpr int Bn  = 8;
constexpr int Cn  = 192;   // hidden channels
constexpr int Tn  = 1024;  // sequence length
constexpr int Hn  = 2;     // heads
constexpr int DKn = 96;    // head dim
constexpr int FCn = 768;   // filter channels
constexpr int Ln  = 6;     // layers
constexpr int WINn = 4;    // rel-attn window
constexpr int QKS = 384;   // QK transposed row stride (Q|K concat)
constexpr int NSPLIT = 4;  // attention s-split (flash-decoding)
constexpr int RN  = Bn * Hn * Tn;  // 16384 attention rows

typedef __hip_bfloat16 bf16;
typedef __attribute__((ext_vector_type(8))) short short8;
typedef __attribute__((ext_vector_type(4))) float f32x4;

// ---------------------------------------------------------------------------
// One-time weight transforms in a single grid-stride kernel (R6).
__global__ void prep_all(
        const float* __restrict__ Wq, const float* __restrict__ Wk,
        const float* __restrict__ Wv, const float* __restrict__ bq,
        const float* __restrict__ bk, const float* __restrict__ bv,
        const float* __restrict__ Wo, const float* __restrict__ w1,
        const float* __restrict__ w2, const float* __restrict__ erk,
        const float* __restrict__ erv,
        bf16* __restrict__ Wqkv, float* __restrict__ bqkv,
        bf16* __restrict__ Wob, bf16* __restrict__ W1t, bf16* __restrict__ W2t,
        bf16* __restrict__ ERKB, bf16* __restrict__ ERVB, float qscale) {
    size_t i = (size_t)blockIdx.x * 256 + threadIdx.x;
    const size_t nW  = (size_t)Ln * 576 * Cn;     // 663,552
    const size_t nB  = (size_t)Ln * 576;
    const size_t WCn = (size_t)Ln * Cn * Cn;      // 221,184
    const size_t WFn = (size_t)Ln * 3 * FCn * Cn; // 2,654,208
    if (i < nW) {        // fused QKV weight (qscale folded into Q)
        int c = i % Cn, f = (i / Cn) % 576, l = i / (Cn * 576);
        float v;
        if (f < 192)      v = Wq[((size_t)l * Cn + f) * Cn + c] * qscale;
        else if (f < 384) v = Wk[((size_t)l * Cn + f - 192) * Cn + c];
        else              v = Wv[((size_t)l * Cn + f - 384) * Cn + c];
        Wqkv[i] = __float2bfloat16(v);
        return;
    }
    i -= nW;
    if (i < nB) {        // fused QKV bias
        int f = i % 576, l = i / 576;
        float v;
        if (f < 192)      v = bq[l * Cn + f] * qscale;
        else if (f < 384) v = bk[l * Cn + f - 192];
        else              v = bv[l * Cn + f - 384];
        bqkv[i] = v;
        return;
    }
    i -= nB;
    if (i < WCn) {       // Wo cast
        Wob[i] = __float2bfloat16(Wo[i]);
        return;
    }
    i -= WCn;
    if (i < WFn) {       // w1 [L][FC][C][3] -> [L][3][FC][C]
        int c = i % Cn;
        int f = (i / Cn) % FCn;
        int ko = (i / (Cn * FCn)) % 3;
        int l = i / (3 * Cn * FCn);
        W1t[i] = __float2bfloat16(w1[(((size_t)(l * FCn + f)) * Cn + c) * 3 + ko]);
        return;
    }
    i -= WFn;
    if (i < WFn) {       // w2 [L][C][FC][3] -> [L][3][C][FC]
        int c = i % FCn;
        int f = (i / FCn) % Cn;
        int ko = (i / (FCn * Cn)) % 3;
        int l = i / (3 * FCn * Cn);
        W2t[i] = __float2bfloat16(w2[(((size_t)(l * Cn + f)) * FCn + c) * 3 + ko]);
        return;
    }
    i -= WFn;
    if (i < (size_t)Ln * 16 * 96) {   // erk -> [L][16][96], rows 9..15 zero
        int d = i % 96, row = (i / 96) % 16, l = i / (96 * 16);
        float v = (row < 9) ? erk[((size_t)l * 9 + row) * 96 + d] : 0.f;
        ERKB[i] = __float2bfloat16(v);
        return;
    }
    i -= (size_t)Ln * 16 * 96;
    if (i < (size_t)Ln * 96 * 32) {   // erv -> [L][96][32] transposed, k 9..31 zero
        int k = i & 31, d = (i >> 5) % 96, l = i / (96 * 32);
        float v = (k < 9) ? erv[((size_t)l * 9 + k) * 96 + d] : 0.f;
        ERVB[i] = __float2bfloat16(v);
    }
}

// ---------------------------------------------------------------------------
// Input: X = x*mask (fp32, NCT) + XT = bf16 transposed [b][t][c]
__global__ __launch_bounds__(256) void cvt_in_k(
        const float* __restrict__ x, const float* __restrict__ mask,
        float* __restrict__ X, bf16* __restrict__ XT) {
    __shared__ float tile[Cn][33];
    const int tid = threadIdx.x, lane = tid & 31, w = tid >> 5;
    const int b = blockIdx.x >> 5;
    const int t0 = (blockIdx.x & 31) * 32;
    const float mk = mask[b * Tn + t0 + lane];
    for (int c = w; c < Cn; c += 8) {
        float v = x[((b * Cn + c) * Tn) + t0 + lane] * mk;
        X[((b * Cn + c) * Tn) + t0 + lane] = v;
        tile[c][lane] = v;
    }
    __syncthreads();
    for (int idx = tid; idx < 32 * Cn; idx += 256) {
        int tl = idx / Cn, c = idx % Cn;
        XT[((size_t)b * Tn + t0 + tl) * Cn + c] = __float2bfloat16(tile[c][tl]);
    }
}

// ---------------------------------------------------------------------------
// MFMA conv1d, LDS-staged, TT=128 for K-heavy convs, T14 async-STAGE (R4).
// MODE 2: bf16 transposed [b][t][CO] out relu(+bias)*mask   [FFN1]
// MODE 4: QKV split: f<384 -> bf16 T (stride QKS) into Y0; else bf16 NCT Y1
//         (used only for layer 0; layers 1..5 get QKV from ffn2_ln_qkv)
template <int KS, int TT, int MODE, int NSP>
__global__ __launch_bounds__(256) void conv_mfma(
        const bf16* __restrict__ Xt, const bf16* __restrict__ W,
        const float* __restrict__ bias, const float* __restrict__ mask,
        void* __restrict__ Y0, void* __restrict__ Y1, int CIN, int CO) {
    constexpr int PAD = KS / 2;
    constexpr int NMB = TT / 16;
    constexpr int AR  = TT + KS - 1;        // A rows staged
    constexpr int RS  = 72;                 // padded row stride (bf16 cols)
    constexpr int NA  = (AR * 8 + 255) / 256;  // per-thread A short8 loads
    constexpr int NB  = KS * 2;                // per-thread B short8 loads
    __shared__ bf16 As[AR][RS];
    __shared__ bf16 Bs[KS][64][RS];

    const int tid = threadIdx.x;
    const int wv = tid >> 6, lane = tid & 63;
    const int m = lane & 15, kq = lane >> 4;
    const int b = blockIdx.z / NSP, ks = blockIdx.z % NSP;
    const int t0 = blockIdx.x * TT;
    const int f0 = blockIdx.y * 64;
    const int f = f0 + wv * 16 + m;

    const bf16* xb = Xt + (size_t)b * Tn * CIN;
    const size_t wko = (size_t)CO * CIN;

    int rA[NA], cA[NA];
    bool vA[NA];
#pragma unroll
    for (int i = 0; i < NA; ++i) {
        int s = tid + i * 256;
        rA[i] = s >> 3; cA[i] = (s & 7) * 8; vA[i] = (s < AR * 8);
    }
    int rB[NB], cB[NB], koB[NB];
#pragma unroll
    for (int i = 0; i < NB; ++i) {
        int s = tid + i * 256;          // always < KS*512
        koB[i] = s >> 9; rB[i] = (s >> 3) & 63; cB[i] = (s & 7) * 8;
    }

    short8 pa[NA], pb[NB];
    const int cbeg = ks * (CIN / NSP);
    const int cend = cbeg + CIN / NSP;

    auto issue = [&](int c0) {
#pragma unroll
        for (int i = 0; i < NA; ++i) {
            short8 v = {0, 0, 0, 0, 0, 0, 0, 0};
            if (vA[i]) {
                int gt = t0 + rA[i] - PAD;
                if (PAD == 0 || (unsigned)gt < (unsigned)Tn)
                    v = *(const short8*)(xb + (size_t)gt * CIN + c0 + cA[i]);
            }
            pa[i] = v;
        }
#pragma unroll
        for (int i = 0; i < NB; ++i)
            pb[i] = *(const short8*)(W + (size_t)koB[i] * wko +
                                     (size_t)(f0 + rB[i]) * CIN + c0 + cB[i]);
    };
    auto commit = [&]() {
#pragma unroll
        for (int i = 0; i < NA; ++i)
            if (vA[i]) *(short8*)&As[rA[i]][cA[i]] = pa[i];
#pragma unroll
        for (int i = 0; i < NB; ++i)
            *(short8*)&Bs[koB[i]][rB[i]][cB[i]] = pb[i];
    };

    f32x4 acc[NMB] = {};

    issue(cbeg);
    commit();
    __syncthreads();

    for (int c0 = cbeg; c0 < cend; c0 += 64) {
        const bool nxt = (c0 + 64 < cend);
        if (nxt) issue(c0 + 64);
#pragma unroll
        for (int kk = 0; kk < 2; ++kk)
#pragma unroll
            for (int ko = 0; ko < KS; ++ko) {
                short8 bfr = *(const short8*)&Bs[ko][wv * 16 + m][kk * 32 + kq * 8];
#pragma unroll
                for (int mb = 0; mb < NMB; ++mb) {
                    short8 afr = *(const short8*)&As[mb * 16 + m + ko][kk * 32 + kq * 8];
                    acc[mb] = __builtin_amdgcn_mfma_f32_16x16x32_bf16(afr, bfr, acc[mb], 0, 0, 0);
                }
            }
        if (nxt) {
            __syncthreads();   // all fragment reads of this chunk complete
            commit();
            __syncthreads();   // staged data visible
        }
    }

    const float bs = bias[f];
    if (MODE == 2) {
        bf16* Y = (bf16*)Y0;
#pragma unroll
        for (int mb = 0; mb < NMB; ++mb)
#pragma unroll
            for (int r = 0; r < 4; ++r) {
                int t = t0 + mb * 16 + kq * 4 + r;
                float v = fmaxf(acc[mb][r] + bs, 0.f) * mask[b * Tn + t];
                Y[((size_t)b * Tn + t) * CO + f] = __float2bfloat16(v);
            }
    } else {  // MODE 4
        if (blockIdx.y < 6) {          // Q|K -> transposed, stride QKS
            bf16* Y = (bf16*)Y0;
#pragma unroll
            for (int mb = 0; mb < NMB; ++mb)
#pragma unroll
                for (int r = 0; r < 4; ++r) {
                    int t = t0 + mb * 16 + kq * 4 + r;
                    Y[((size_t)b * Tn + t) * QKS + f] = __float2bfloat16(acc[mb][r] + bs);
                }
        } else {                        // V -> bf16 NCT
            bf16* Y = (bf16*)Y1 + ((size_t)b * Cn + f - 384) * Tn;
#pragma unroll
            for (int mb = 0; mb < NMB; ++mb) {
                int t = t0 + mb * 16 + kq * 4;
                bf16 tmp[4];
#pragma unroll
                for (int r = 0; r < 4; ++r) tmp[r] = __float2bfloat16(acc[mb][r] + bs);
                *(uint2*)(Y + t) = *(uint2*)tmp;
            }
        }
    }
}

// ---------------------------------------------------------------------------
// R8: wo_ln_k at 512 threads / 8 waves (2 waves/SIMD). Waves map as
// 4 f-groups (48 ch) x 2 t-groups (16 rows); per-wave acc[3].
__global__ __launch_bounds__(512) void wo_ln_k(
        const bf16* __restrict__ Op, const float* __restrict__ Lp,
        const bf16* __restrict__ W, const float* __restrict__ bias,
        float* __restrict__ X, const float* __restrict__ G,
        const float* __restrict__ Bt, const float* __restrict__ mask,
        bf16* __restrict__ XT) {
    __shared__ bf16 As[32][72];       // combined attn out [t][c-chunk]
    __shared__ bf16 Bs[192][72];      // Wo panel [f][c-chunk]
    __shared__ float sm1[8][16];
    __shared__ float sm2[8][16];

    const int tid = threadIdx.x;
    const int wv = tid >> 6, lane = tid & 63;
    const int m = lane & 15, quad = lane >> 4;
    const int fg = wv & 3, tg = wv >> 2;
    const int b = blockIdx.x & 7;
    const int t0 = (blockIdx.x >> 3) * 32;

    const bool vA = (tid < 256);
    const int rA = tid >> 3, cA = (tid & 7) * 8;   // A: 32 rows x 8 short8
    short8 pa6[4]; float pl6[4];
    short8 pb[3];                                   // B: 1536 short8 / 512

    auto issue = [&](int c0) {
        if (vA) {
            int c = c0 + cA;
            int hh = (c >= 96) ? 1 : 0;
            int rid = (b * Hn + hh) * Tn + t0 + rA;
            int d0 = c - 96 * hh;
#pragma unroll
            for (int sp = 0; sp < 4; ++sp) {
                pa6[sp] = *(const short8*)(Op + ((size_t)sp * RN + rid) * 96 + d0);
                pl6[sp] = Lp[sp * RN + rid];
            }
        }
#pragma unroll
        for (int i = 0; i < 3; ++i) {
            int s = tid + i * 512;
            pb[i] = *(const short8*)(W + (size_t)(s >> 3) * Cn + c0 + (s & 7) * 8);
        }
    };
    auto commit = [&]() {
        if (vA) {
            float denom = pl6[0] + pl6[1] + pl6[2] + pl6[3];
            float inv = 1.f / fmaxf(denom, 1e-30f);
            bf16 tmp[8];
#pragma unroll
            for (int e = 0; e < 8; ++e) {
                float o = 0.f;
#pragma unroll
                for (int sp = 0; sp < 4; ++sp)
                    o += __bfloat162float(((const bf16*)&pa6[sp])[e]);
                tmp[e] = __float2bfloat16(o * inv);
            }
            *(short8*)&As[rA][cA] = *(const short8*)tmp;
        }
#pragma unroll
        for (int i = 0; i < 3; ++i) {
            int s = tid + i * 512;
            *(short8*)&Bs[s >> 3][(s & 7) * 8] = pb[i];
        }
    };

    f32x4 acc[3] = {};

    issue(0);
    commit();
    __syncthreads();
    for (int c0 = 0; c0 < Cn; c0 += 64) {
        const bool nxt = (c0 + 64 < Cn);
        if (nxt) issue(c0 + 64);
#pragma unroll
        for (int kk = 0; kk < 2; ++kk) {
            short8 afr = *(const short8*)&As[tg * 16 + m][kk * 32 + quad * 8];
#pragma unroll
            for (int fb = 0; fb < 3; ++fb) {
                short8 bfr = *(const short8*)&Bs[fg * 48 + fb * 16 + m][kk * 32 + quad * 8];
                acc[fb] = __builtin_amdgcn_mfma_f32_16x16x32_bf16(afr, bfr, acc[fb], 0, 0, 0);
            }
        }
        if (nxt) {
            __syncthreads();
            commit();
            __syncthreads();
        }
    }

    // bias + residual; per-t LN stats over this lane's 3 channels
    const int tq = t0 + tg * 16 + quad * 4;
    float s1[4] = {}, s2[4] = {};
#pragma unroll
    for (int fb = 0; fb < 3; ++fb) {
        const int f = fg * 48 + fb * 16 + m;
        const float bsv = bias[f];
        float4 xv = *(const float4*)(X + ((size_t)(b * Cn + f)) * Tn + tq);
        acc[fb][0] += bsv + xv.x;
        acc[fb][1] += bsv + xv.y;
        acc[fb][2] += bsv + xv.z;
        acc[fb][3] += bsv + xv.w;
#pragma unroll
        for (int r = 0; r < 4; ++r) {
            float v = acc[fb][r];
            s1[r] += v;
            s2[r] += v * v;
        }
    }
#pragma unroll
    for (int r = 0; r < 4; ++r)
#pragma unroll
        for (int mk = 1; mk < 16; mk <<= 1) {
            s1[r] += __shfl_xor(s1[r], mk);
            s2[r] += __shfl_xor(s2[r], mk);
        }
    if (m == 0) {
#pragma unroll
        for (int r = 0; r < 4; ++r) {
            sm1[wv][quad * 4 + r] = s1[r];
            sm2[wv][quad * 4 + r] = s2[r];
        }
    }
    __syncthreads();
    float mean[4], rsv[4];
    float4 mk4 = *(const float4*)(mask + b * Tn + tq);
    float mtv[4] = {mk4.x, mk4.y, mk4.z, mk4.w};
#pragma unroll
    for (int r = 0; r < 4; ++r) {
        int tt = quad * 4 + r;
        float a = sm1[tg * 4 + 0][tt] + sm1[tg * 4 + 1][tt] +
                  sm1[tg * 4 + 2][tt] + sm1[tg * 4 + 3][tt];
        float q = sm2[tg * 4 + 0][tt] + sm2[tg * 4 + 1][tt] +
                  sm2[tg * 4 + 2][tt] + sm2[tg * 4 + 3][tt];
        float mn = a / Cn;
        mean[r] = mn;
        rsv[r] = rsqrtf(q / Cn - mn * mn + 1e-5f);
    }
#pragma unroll
    for (int fb = 0; fb < 3; ++fb) {
        const int f = fg * 48 + fb * 16 + m;
        const float gv = G[f], bv = Bt[f];
        float y[4];
#pragma unroll
        for (int r = 0; r < 4; ++r)
            y[r] = (acc[fb][r] - mean[r]) * rsv[r] * gv + bv;
        float4 xo;
        xo.x = y[0]; xo.y = y[1]; xo.z = y[2]; xo.w = y[3];
        *(float4*)(X + ((size_t)(b * Cn + f)) * Tn + tq) = xo;
#pragma unroll
        for (int r = 0; r < 4; ++r)
            XT[((size_t)b * Tn + tq + r) * Cn + f] =
                __float2bfloat16(y[r] * mtv[r]);
    }
}

// ---------------------------------------------------------------------------
// R12: ffn2_ln_qkv with REGISTER-TILED B (no Bs LDS, no B barrier).
// The weight panel has a 1:1 wave<->rows mapping (wave fg reads only rows
// fg*32..+32), so LDS staging of B was pure barrier/drain overhead —
// R10/R11 showed the commit->barrier chain is the limiter. Now each wave
// loads its 12 B-frags per chunk directly from global (16 rows x 64 B
// segments) into named register sets, prefetched one chunk ahead; a
// wave's B-loads only wait at their own first use, one chunk later, and
// keep filling while other waves sit at the (tiny) A-tile barrier.
// Phase-2 QKV same treatment: zero barriers after the single Ys sync.
// LDS 101.9 KB -> ~19 KB. MFMA operand values and accumulation order
// bit-identical to R10.
__global__ __launch_bounds__(768, 3) void ffn2_ln_qkv(
        const bf16* __restrict__ Hc, const bf16* __restrict__ W,
        const float* __restrict__ bias, float* __restrict__ X,
        const float* __restrict__ G, const float* __restrict__ Bt,
        const float* __restrict__ mask,
        const bf16* __restrict__ Wqn, const float* __restrict__ bqn,
        bf16* __restrict__ QKT, bf16* __restrict__ Vb,
        float* __restrict__ OUT) {
    __shared__ bf16 As[34][72];        // hidden rows t0-1..t0+32, c-chunk
    __shared__ float sm1[12][16];
    __shared__ float sm2[12][16];
    __shared__ bf16 Ys[32][200];       // LN2 output tile [t][c] (phase 2 A)

    const int tid = threadIdx.x;
    const int wv = tid >> 6, lane = tid & 63;
    const int m = lane & 15, quad = lane >> 4;
    const int fg = wv % 6, tg = wv / 6;      // 6 f-groups x 2 t-groups
    const int b = blockIdx.x & 7;
    const int t0 = (blockIdx.x >> 3) * 32;

    const bf16* hb = Hc + (size_t)b * Tn * FCn;
    // per-wave B base: row fg*32 + m (+fb*16), byte col quad*8 (+c0+kk*32)
    const bf16* wB = W + (size_t)(fg * 32 + m) * FCn + quad * 8;

    const bool vA = (tid < 272);
    short8 paA, paB;
    auto issueA = [&](int c0, short8& pa_) {
        short8 v = {0, 0, 0, 0, 0, 0, 0, 0};
        if (vA) {
            int gt = t0 + (tid >> 3) - 1;
            if ((unsigned)gt < (unsigned)Tn)
                v = *(const short8*)(hb + (size_t)gt * FCn + c0 + (tid & 7) * 8);
        }
        pa_ = v;
    };
    auto commitA = [&](short8& pa_) {
        if (vA) *(short8*)&As[tid >> 3][(tid & 7) * 8] = pa_;
    };

    short8 bS0[12], bS1[12];
    auto issueB = [&](short8 (&s)[12], int c0) {
#pragma unroll
        for (int ko = 0; ko < 3; ++ko)
#pragma unroll
            for (int fb = 0; fb < 2; ++fb)
#pragma unroll
                for (int kk = 0; kk < 2; ++kk)
                    s[ko * 4 + fb * 2 + kk] = *(const short8*)(
                        wB + (size_t)ko * Cn * FCn + (size_t)fb * 16 * FCn +
                        c0 + kk * 32);
    };

    f32x4 acc[2] = {};
    auto mfma_chunk = [&](short8 (&s)[12]) {
#pragma unroll
        for (int kk = 0; kk < 2; ++kk)
#pragma unroll
            for (int ko = 0; ko < 3; ++ko) {
                short8 afr = *(const short8*)&As[tg * 16 + m + ko][kk * 32 + quad * 8];
#pragma unroll
                for (int fb = 0; fb < 2; ++fb)
                    acc[fb] = __builtin_amdgcn_mfma_f32_16x16x32_bf16(
                        afr, s[ko * 4 + fb * 2 + kk], acc[fb], 0, 0, 0);
            }
    };

    // prologue: As=chunk0; bS0=B(0), bS1=B(64) in flight; paB=A(64)
    issueA(0, paA);
    issueB(bS0, 0);
    issueB(bS1, 64);
    commitA(paA);
    __syncthreads();
    issueA(64, paB);

    // 12 chunks, 2 per iteration
    for (int it = 0; it < 6; ++it) {
        const int c0 = it * 128;
        const bool more = (it < 5);
        mfma_chunk(bS0);                   // chunk c0
        if (more) issueB(bS0, c0 + 128);   // refill for chunk c0+128
        __syncthreads();                   // As chunk-c0 reads complete
        commitA(paB);                      // As = chunk c0+64
        __syncthreads();
        if (more) issueA(c0 + 128, paA);
        mfma_chunk(bS1);                   // chunk c0+64
        if (more) {
            issueB(bS1, c0 + 192);
            __syncthreads();
            commitA(paA);                  // As = chunk c0+128
            __syncthreads();
            issueA(c0 + 192, paB);
        }
    }

    // y = (conv + bias)*mask; v = X + y; LN stats over channels
    const int tq = t0 + tg * 16 + quad * 4;
    float4 mk4 = *(const float4*)(mask + b * Tn + tq);
    float mtv[4] = {mk4.x, mk4.y, mk4.z, mk4.w};
    float s1[4] = {}, s2[4] = {};
#pragma unroll
    for (int fb = 0; fb < 2; ++fb) {
        const int f = fg * 32 + fb * 16 + m;
        const float bsv = bias[f];
        float4 xv = *(const float4*)(X + ((size_t)(b * Cn + f)) * Tn + tq);
        acc[fb][0] = xv.x + (acc[fb][0] + bsv) * mtv[0];
        acc[fb][1] = xv.y + (acc[fb][1] + bsv) * mtv[1];
        acc[fb][2] = xv.z + (acc[fb][2] + bsv) * mtv[2];
        acc[fb][3] = xv.w + (acc[fb][3] + bsv) * mtv[3];
#pragma unroll
        for (int r = 0; r < 4; ++r) {
            float v = acc[fb][r];
            s1[r] += v;
            s2[r] += v * v;
        }
    }
#pragma unroll
    for (int r = 0; r < 4; ++r)
#pragma unroll
        for (int mk = 1; mk < 16; mk <<= 1) {
            s1[r] += __shfl_xor(s1[r], mk);
            s2[r] += __shfl_xor(s2[r], mk);
        }
    if (m == 0) {
#pragma unroll
        for (int r = 0; r < 4; ++r) {
            sm1[wv][quad * 4 + r] = s1[r];
            sm2[wv][quad * 4 + r] = s2[r];
        }
    }
    __syncthreads();
    float mean[4], rsv[4];
#pragma unroll
    for (int r = 0; r < 4; ++r) {
        int tt = quad * 4 + r;
        float a = 0.f, q = 0.f;
#pragma unroll
        for (int j = 0; j < 6; ++j) {
            a += sm1[tg * 6 + j][tt];
            q += sm2[tg * 6 + j][tt];
        }
        float mn = a / Cn;
        mean[r] = mn;
        rsv[r] = rsqrtf(q / Cn - mn * mn + 1e-5f);
    }

    float y3[2][4];
#pragma unroll
    for (int fb = 0; fb < 2; ++fb) {
        const int f = fg * 32 + fb * 16 + m;
        const float gv = G[f], bv = Bt[f];
#pragma unroll
        for (int r = 0; r < 4; ++r)
            y3[fb][r] = (acc[fb][r] - mean[r]) * rsv[r] * gv + bv;
    }

    if (OUT) {      // final layer: OUT = LN(...)*mask, NCT fp32; no QKV
#pragma unroll
        for (int fb = 0; fb < 2; ++fb) {
            const int f = fg * 32 + fb * 16 + m;
            float4 xo;
            xo.x = y3[fb][0] * mtv[0]; xo.y = y3[fb][1] * mtv[1];
            xo.z = y3[fb][2] * mtv[2]; xo.w = y3[fb][3] * mtv[3];
            *(float4*)(OUT + ((size_t)(b * Cn + f)) * Tn + tq) = xo;
        }
        return;
    }

    // write X (residual stream for next layer's wo_ln_k)
#pragma unroll
    for (int fb = 0; fb < 2; ++fb) {
        const int f = fg * 32 + fb * 16 + m;
        float4 xo;
        xo.x = y3[fb][0]; xo.y = y3[fb][1]; xo.z = y3[fb][2]; xo.w = y3[fb][3];
        *(float4*)(X + ((size_t)(b * Cn + f)) * Tn + tq) = xo;
    }

    // ---- phase 2: QKV 1x1 conv for the NEXT layer (register-tiled B) ----
    const bf16* wQ = Wqn + (size_t)(fg * 96 + m) * Cn + quad * 8;
    short8 qS0[12], qS1[12];
    auto issueQ = [&](short8 (&s)[12], int c0) {
#pragma unroll
        for (int fb = 0; fb < 6; ++fb)
#pragma unroll
            for (int kk = 0; kk < 2; ++kk)
                s[fb * 2 + kk] = *(const short8*)(
                    wQ + (size_t)fb * 16 * Cn + c0 + kk * 32);
    };

    f32x4 acc2[6] = {};
    auto qkv_chunk = [&](short8 (&s)[12], int c0) {
#pragma unroll
        for (int kk = 0; kk < 2; ++kk) {
            short8 afr = *(const short8*)&Ys[tg * 16 + m][c0 + kk * 32 + quad * 8];
#pragma unroll
            for (int fb = 0; fb < 6; ++fb)
                acc2[fb] = __builtin_amdgcn_mfma_f32_16x16x32_bf16(
                    afr, s[fb * 2 + kk], acc2[fb], 0, 0, 0);
        }
    };

    issueQ(qS0, 0);
    // drop y (unmasked, matching old XT semantics) into the LDS A-tile
#pragma unroll
    for (int fb = 0; fb < 2; ++fb) {
        const int f = fg * 32 + fb * 16 + m;
#pragma unroll
        for (int r = 0; r < 4; ++r)
            Ys[tg * 16 + quad * 4 + r][f] = __float2bfloat16(y3[fb][r]);
    }
    issueQ(qS1, 64);
    __syncthreads();     // Ys visible (only barrier in phase 2)
    qkv_chunk(qS0, 0);
    issueQ(qS0, 128);
    qkv_chunk(qS1, 64);
    qkv_chunk(qS0, 128);

    // epilogue: QKT transposed (f<384) / Vb NCT (f>=384), bias added
#pragma unroll
    for (int fb = 0; fb < 6; ++fb) {
        const int f = fg * 96 + fb * 16 + m;
        const float bsv = bqn[f];
        if (f < 384) {
#pragma unroll
            for (int r = 0; r < 4; ++r)
                QKT[((size_t)b * Tn + tq + r) * QKS + f] =
                    __float2bfloat16(acc2[fb][r] + bsv);
        } else {
            bf16 tmp[4];
#pragma unroll
            for (int r = 0; r < 4; ++r) tmp[r] = __float2bfloat16(acc2[fb][r] + bsv);
            *(uint2*)(Vb + ((size_t)b * Cn + f - 384) * Tn + tq) = *(uint2*)tmp;
        }
    }
}

// ---------------------------------------------------------------------------
// MFMA flash attention. R8: 8 waves / QBLK=128 per block (512 threads,
// grid 512). XCD swizzle (R2), T14 async-STAGE (R2), rel-V via MFMA (R3),
// ones-MFMA rowsum + gating + setprio (R5). FIXED-MAX softmax.
// Writes UNNORMALIZED partials: Op bf16 [sp][rid][96], Lp fp32 [sp][rid].
__global__ __launch_bounds__(512) void attn_mfma(
        const bf16* __restrict__ QK, const bf16* __restrict__ V,
        const float* __restrict__ mask, const bf16* __restrict__ erkb,
        const bf16* __restrict__ ervb, bf16* __restrict__ Op,
        float* __restrict__ Lp, int layer) {
    __shared__ bf16 Ks[64][100];      // K chunk [s][d]
    __shared__ bf16 Vs[96][68];       // V chunk [d][s]
    __shared__ float rq[8][16][17];   // per-wave rel-K band: [m][dd]
    __shared__ bf16 pT[8][16][68];    // per-wave P: [m][s]
    __shared__ bf16 pdg[8][16][16];   // per-wave rel-V band: [m][dd], 9..15 zero
    // LDS total: 56064 B -> 2 blocks/CU

    const int tid = threadIdx.x, wv = tid >> 6, lane = tid & 63;
    const int col = lane & 15, quad = lane >> 4;
    // XCD-bijective swizzle (512 = 8 XCD x 64)
    const int w = (blockIdx.x & 7) * 64 + (blockIdx.x >> 3);
    const int t0 = (w & 7) * 128;
    const int yz = w >> 3;
    const int h = yz & 1;
    const int z = yz >> 1;
    const int b = z >> 2, sp = z & 3;
    const int hd = h * DKn;
    const int t0w = t0 + wv * 16;

    *(uint2*)&pdg[wv][col][quad * 4] = (uint2){0, 0};

    const bool g2 = (tid < 256);
    int rK[2], cK[2], rV[2], cV[2];
    {
        int s = tid;
        rK[0] = s / 12; cK[0] = (s % 12) * 8;   // 64 rows x 96 cols
        rV[0] = s >> 3; cV[0] = (s & 7) * 8;    // 96 rows x 64 cols
        s = tid + 512;
        rK[1] = s / 12; cK[1] = (s % 12) * 8;   // valid only if g2
        rV[1] = s >> 3; cV[1] = (s & 7) * 8;
    }
    const bf16* kbase = QK + (size_t)b * Tn * QKS + 192 + hd;
    const bf16* vbase = V + ((size_t)b * Cn + hd) * Tn;

    short8 kst[2], vst[2];
    const int sbeg = sp * (Tn / NSPLIT);
    const int send = sbeg + Tn / NSPLIT;

    kst[0] = *(const short8*)(kbase + (size_t)(sbeg + rK[0]) * QKS + cK[0]);
    vst[0] = *(const short8*)(vbase + (size_t)rV[0] * Tn + sbeg + cV[0]);
    if (g2) {
        kst[1] = *(const short8*)(kbase + (size_t)(sbeg + rK[1]) * QKS + cK[1]);
        vst[1] = *(const short8*)(vbase + (size_t)rV[1] * Tn + sbeg + cV[1]);
    }

    short8 aq[3];
    {
        const bf16* qrow = QK + ((size_t)b * Tn + t0w + col) * QKS + hd + quad * 8;
#pragma unroll
        for (int kd = 0; kd < 3; ++kd) aq[kd] = *(const short8*)(qrow + kd * 32);
    }
    {
        const bf16* erow = erkb + ((size_t)layer * 16 + col) * 96 + quad * 8;
        f32x4 R = {};
#pragma unroll
        for (int kd = 0; kd < 3; ++kd) {
            short8 be = *(const short8*)(erow + kd * 32);
            R = __builtin_amdgcn_mfma_f32_16x16x32_bf16(aq[kd], be, R, 0, 0, 0);
        }
#pragma unroll
        for (int r = 0; r < 4; ++r) rq[wv][quad * 4 + r][col] = R[r];
    }
    float mtv[4];
#pragma unroll
    for (int r = 0; r < 4; ++r) mtv[r] = mask[b * Tn + t0w + quad * 4 + r];
    const bool qok = __all(mtv[0] != 0.f && mtv[1] != 0.f &&
                           mtv[2] != 0.f && mtv[3] != 0.f);
    int okbits = 0;
    if (qok) {
#pragma unroll
        for (int ch = 0; ch < 4; ++ch) {
            int sc = b * Tn + sbeg + ch * 64 + col;
            float a0 = mask[sc], a1 = mask[sc + 16], a2 = mask[sc + 32], a3 = mask[sc + 48];
            if (__all(a0 != 0.f && a1 != 0.f && a2 != 0.f && a3 != 0.f))
                okbits |= 1 << ch;
        }
    }

    *(short8*)&Ks[rK[0]][cK[0]] = kst[0];
    *(short8*)&Vs[rV[0]][cV[0]] = vst[0];
    if (g2) {
        *(short8*)&Ks[rK[1]][cK[1]] = kst[1];
        *(short8*)&Vs[rV[1]][cV[1]] = vst[1];
    }
    __syncthreads();

    f32x4 O[6] = {};
    f32x4 Osum = {};
    short8 ones;
#pragma unroll
    for (int j = 0; j < 8; ++j) ones[j] = (short)0x3F80;   // bf16 1.0

    for (int s0 = sbeg; s0 < send; s0 += 64) {
        const bool nxt = (s0 + 64 < send);
        if (nxt) {
            kst[0] = *(const short8*)(kbase + (size_t)(s0 + 64 + rK[0]) * QKS + cK[0]);
            vst[0] = *(const short8*)(vbase + (size_t)rV[0] * Tn + s0 + 64 + cV[0]);
            if (g2) {
                kst[1] = *(const short8*)(kbase + (size_t)(s0 + 64 + rK[1]) * QKS + cK[1]);
                vst[1] = *(const short8*)(vbase + (size_t)rV[1] * Tn + s0 + 64 + cV[1]);
            }
        }

        f32x4 S[4] = {};
        __builtin_amdgcn_s_setprio(1);
#pragma unroll
        for (int nb = 0; nb < 4; ++nb)
#pragma unroll
            for (int kd = 0; kd < 3; ++kd) {
                short8 bkf = *(const short8*)&Ks[16 * nb + col][kd * 32 + quad * 8];
                S[nb] = __builtin_amdgcn_mfma_f32_16x16x32_bf16(aq[kd], bkf, S[nb], 0, 0, 0);
            }
        __builtin_amdgcn_s_setprio(0);

        const bool diag = (s0 <= t0w + 15 + WINn) && (s0 + 63 >= t0w - WINn);
        if (diag) {
#pragma unroll
            for (int nb = 0; nb < 4; ++nb) {
                const int sg = s0 + 16 * nb + col;
#pragma unroll
                for (int r = 0; r < 4; ++r) {
                    int dd = sg - (t0w + quad * 4 + r) + WINn;
                    if ((unsigned)dd <= 2u * WINn) S[nb][r] += rq[wv][quad * 4 + r][dd];
                }
            }
        }
        if (!((okbits >> ((s0 - sbeg) >> 6)) & 1)) {
#pragma unroll
            for (int nb = 0; nb < 4; ++nb) {
                const float msv = mask[b * Tn + s0 + 16 * nb + col];
#pragma unroll
                for (int r = 0; r < 4; ++r)
                    if (msv * mtv[r] == 0.f) S[nb][r] = -1e4f;
            }
        }

        if (diag) {
#pragma unroll
            for (int nb = 0; nb < 4; ++nb) {
                const int sg = s0 + 16 * nb + col;
#pragma unroll
                for (int r = 0; r < 4; ++r) {
                    bf16 pb_ = __float2bfloat16(__expf(S[nb][r]));
                    pT[wv][quad * 4 + r][16 * nb + col] = pb_;
                    int dd = sg - (t0w + quad * 4 + r) + WINn;
                    if ((unsigned)dd <= 2u * WINn) pdg[wv][quad * 4 + r][dd] = pb_;
                }
            }
        } else {
#pragma unroll
            for (int nb = 0; nb < 4; ++nb)
#pragma unroll
                for (int r = 0; r < 4; ++r)
                    pT[wv][quad * 4 + r][16 * nb + col] =
                        __float2bfloat16(__expf(S[nb][r]));
        }

        short8 aP[2];
#pragma unroll
        for (int kk = 0; kk < 2; ++kk)
            aP[kk] = *(const short8*)&pT[wv][col][kk * 32 + quad * 8];
        __builtin_amdgcn_s_setprio(1);
#pragma unroll
        for (int nd = 0; nd < 6; ++nd)
#pragma unroll
            for (int kk = 0; kk < 2; ++kk) {
                short8 bvf = *(const short8*)&Vs[16 * nd + col][kk * 32 + quad * 8];
                O[nd] = __builtin_amdgcn_mfma_f32_16x16x32_bf16(aP[kk], bvf, O[nd], 0, 0, 0);
            }
#pragma unroll
        for (int kk = 0; kk < 2; ++kk)
            Osum = __builtin_amdgcn_mfma_f32_16x16x32_bf16(aP[kk], ones, Osum, 0, 0, 0);
        __builtin_amdgcn_s_setprio(0);

        __syncthreads();
        if (nxt) {
            *(short8*)&Ks[rK[0]][cK[0]] = kst[0];
            *(short8*)&Vs[rV[0]][cV[0]] = vst[0];
            if (g2) {
                *(short8*)&Ks[rK[1]][cK[1]] = kst[1];
                *(short8*)&Vs[rV[1]][cV[1]] = vst[1];
            }
            __syncthreads();
        }
    }

    // rel-V band contribution: O += pdg(16x16, k 9..15 zero) . ERVB(k x 96)
    {
        short8 ad = {0, 0, 0, 0, 0, 0, 0, 0};
        if (quad < 2) ad = *(const short8*)&pdg[wv][col][quad * 8];
        const bf16* eb = ervb + (size_t)layer * 96 * 32 + (size_t)col * 32 + quad * 8;
#pragma unroll
        for (int nd = 0; nd < 6; ++nd) {
            short8 bd = *(const short8*)(eb + (size_t)nd * 16 * 32);
            O[nd] = __builtin_amdgcn_mfma_f32_16x16x32_bf16(ad, bd, O[nd], 0, 0, 0);
        }
    }

    // epilogue: write unnormalized partials (Lp row-sums come from Osum)
    const int rbase = (b * Hn + h) * Tn + t0w;
#pragma unroll
    for (int r = 0; r < 4; ++r) {
        const int rid = rbase + quad * 4 + r;
        bf16* dst = Op + ((size_t)sp * RN + rid) * 96 + col;
#pragma unroll
        for (int nd = 0; nd < 6; ++nd)
            dst[16 * nd] = __float2bfloat16(O[nd][r]);
        if (col == 0) Lp[sp * RN + rid] = Osum[r];
    }
}

// ---------------------------------------------------------------------------
extern "C" void kernel_launch(void* const* d_in, const int* in_sizes, int n_in,
                              void* d_out, int out_size, void* d_ws, size_t ws_size,
                              hipStream_t stream) {
    const float* x    = (const float*)d_in[0];
    const float* mask = (const float*)d_in[1];
    const float* Wq   = (const float*)d_in[2];
    const float* bq   = (const float*)d_in[3];
    const float* Wk   = (const float*)d_in[4];
    const float* bk   = (const float*)d_in[5];
    const float* Wv   = (const float*)d_in[6];
    const float* bv   = (const float*)d_in[7];
    const float* Wo   = (const float*)d_in[8];
    const float* bo   = (const float*)d_in[9];
    const float* erk  = (const float*)d_in[10];
    const float* erv  = (const float*)d_in[11];
    const float* ln1g = (const float*)d_in[12];
    const float* ln1b = (const float*)d_in[13];
    const float* w1   = (const float*)d_in[14];
    const float* b1   = (const float*)d_in[15];
    const float* w2   = (const float*)d_in[16];
    const float* b2   = (const float*)d_in[17];
    const float* ln2g = (const float*)d_in[18];
    const float* ln2b = (const float*)d_in[19];

    const size_t N = (size_t)Bn * Cn * Tn;         // 1,572,864
    const int WC = Ln * Cn * Cn;                   // 221,184
    const size_t WF = (size_t)Ln * 3 * FCn * Cn;   // 2,654,208
    const size_t WQKV = (size_t)Ln * 576 * Cn;     // 663,552
    const size_t NSCR = (size_t)Bn * Tn * FCn;     // 6,291,456 == NSPLIT*RN*96

    float* X    = (float*)d_ws;
    float* Yb   = X + N;                           // (unused since R7)
    float* bqkv = Yb + N;                          // L*576 floats
    float* Lp   = bqkv + Ln * 576;                 // NSPLIT*RN floats
    bf16* p16 = (bf16*)(Lp + (size_t)NSPLIT * RN);
    bf16* XT   = p16; p16 += N;
    bf16* QKT  = p16; p16 += (size_t)Bn * Tn * QKS;  // 2N bf16
    bf16* Vb   = p16; p16 += N;
    bf16* AT   = p16; p16 += N;      // (unused; kept for layout)
    bf16* SCR  = p16; p16 += NSCR;   // shared: attn O-partials <-> FFN hidden
    bf16* Wqkv = p16; p16 += WQKV;
    bf16* Wob  = p16; p16 += WC;
    bf16* W1t  = p16; p16 += WF;
    bf16* W2t  = p16; p16 += WF;
    bf16* ERKB = p16; p16 += Ln * 16 * 96;
    bf16* ERVB = p16; p16 += Ln * 96 * 32;
    (void)AT; (void)Yb;

    const float qscale = 0.10206207261596575f;  // 1/sqrt(96)

    // one-time transforms: single fused dispatch
    const size_t nprep = WQKV + Ln * 576 + WC + 2 * WF +
                         (size_t)Ln * 16 * 96 + (size_t)Ln * 96 * 32;
    prep_all<<<(int)((nprep + 255) / 256), 256, 0, stream>>>(
        Wq, Wk, Wv, bq, bk, bv, Wo, w1, w2, erk, erv,
        Wqkv, bqkv, Wob, W1t, W2t, ERKB, ERVB, qscale);
    cvt_in_k<<<Bn * 32, 256, 0, stream>>>(x, mask, X, XT);

    // layer 0's QKV from XT (standalone conv); layers 1..5 get QKV fused
    // into the previous layer's ffn2_ln_qkv.
    conv_mfma<1, 128, 4, 1><<<dim3(Tn / 128, 9, Bn), 256, 0, stream>>>(
        XT, Wqkv, bqkv, nullptr, QKT, Vb, Cn, 576);

    for (int l = 0; l < Ln; ++l) {
        attn_mfma<<<dim3(512), 512, 0, stream>>>(
            QKT, Vb, mask, ERKB, ERVB, SCR, Lp, l);
        // fused: split-combine + Wo conv + residual + LN1 + X/XT write
        wo_ln_k<<<256, 512, 0, stream>>>(
            SCR, Lp, Wob + (size_t)l * Cn * Cn, bo + l * Cn,
            X, ln1g + l * Cn, ln1b + l * Cn, mask, XT);
        conv_mfma<3, 128, 2, 1><<<dim3(Tn / 128, FCn / 64, Bn), 256, 0, stream>>>(
            XT, W1t + (size_t)l * 3 * FCn * Cn, b1 + l * FCn, mask, SCR, nullptr, Cn, FCn);
        // fused: FFN2 conv + mask + residual + LN2 + next layer's QKV
        const bool last = (l == Ln - 1);
        ffn2_ln_qkv<<<256, 768, 0, stream>>>(
            SCR, W2t + (size_t)l * 3 * Cn * FCn, b2 + l * Cn,
            X, ln2g + l * Cn, ln2b + l * Cn, mask,
            last ? nullptr : (Wqkv + (size_t)(l + 1) * 576 * Cn),
            last ? nullptr : (bqkv + (l + 1) * 576),
            QKT, Vb,
            last ? (float*)d_out : nullptr);
    }
}

// Round 13
// 614.157 us; speedup vs baseline: 1.3134x; 1.3134x over previous
//
#include <hip/hip_runtime.h>
#include <hip/hip_bf16.h>

// Problem constants
constexpr int Bn  = 8;
constexpr int Cn  = 192;   // hidden channels
constexpr int Tn  = 1024;  // sequence length
constexpr int Hn  = 2;     // heads
constexpr int DKn = 96;    // head dim
constexpr int FCn = 768;   // filter channels
constexpr int Ln  = 6;     // layers
constexpr int WINn = 4;    // rel-attn window
constexpr int QKS = 384;   // QK transposed row stride (Q|K concat)
constexpr int NSPLIT = 4;  // attention s-split (flash-decoding)
constexpr int RN  = Bn * Hn * Tn;  // 16384 attention rows

typedef __hip_bfloat16 bf16;
typedef __attribute__((ext_vector_type(8))) short short8;
typedef __attribute__((ext_vector_type(4))) float f32x4;

// ---------------------------------------------------------------------------
// One-time weight transforms in a single grid-stride kernel (R6).
__global__ void prep_all(
        const float* __restrict__ Wq, const float* __restrict__ Wk,
        const float* __restrict__ Wv, const float* __restrict__ bq,
        const float* __restrict__ bk, const float* __restrict__ bv,
        const float* __restrict__ Wo, const float* __restrict__ w1,
        const float* __restrict__ w2, const float* __restrict__ erk,
        const float* __restrict__ erv,
        bf16* __restrict__ Wqkv, float* __restrict__ bqkv,
        bf16* __restrict__ Wob, bf16* __restrict__ W1t, bf16* __restrict__ W2t,
        bf16* __restrict__ ERKB, bf16* __restrict__ ERVB, float qscale) {
    size_t i = (size_t)blockIdx.x * 256 + threadIdx.x;
    const size_t nW  = (size_t)Ln * 576 * Cn;     // 663,552
    const size_t nB  = (size_t)Ln * 576;
    const size_t WCn = (size_t)Ln * Cn * Cn;      // 221,184
    const size_t WFn = (size_t)Ln * 3 * FCn * Cn; // 2,654,208
    if (i < nW) {        // fused QKV weight (qscale folded into Q)
        int c = i % Cn, f = (i / Cn) % 576, l = i / (Cn * 576);
        float v;
        if (f < 192)      v = Wq[((size_t)l * Cn + f) * Cn + c] * qscale;
        else if (f < 384) v = Wk[((size_t)l * Cn + f - 192) * Cn + c];
        else              v = Wv[((size_t)l * Cn + f - 384) * Cn + c];
        Wqkv[i] = __float2bfloat16(v);
        return;
    }
    i -= nW;
    if (i < nB) {        // fused QKV bias
        int f = i % 576, l = i / 576;
        float v;
        if (f < 192)      v = bq[l * Cn + f] * qscale;
        else if (f < 384) v = bk[l * Cn + f - 192];
        else              v = bv[l * Cn + f - 384];
        bqkv[i] = v;
        return;
    }
    i -= nB;
    if (i < WCn) {       // Wo cast
        Wob[i] = __float2bfloat16(Wo[i]);
        return;
    }
    i -= WCn;
    if (i < WFn) {       // w1 [L][FC][C][3] -> [L][3][FC][C]
        int c = i % Cn;
        int f = (i / Cn) % FCn;
        int ko = (i / (Cn * FCn)) % 3;
        int l = i / (3 * Cn * FCn);
        W1t[i] = __float2bfloat16(w1[(((size_t)(l * FCn + f)) * Cn + c) * 3 + ko]);
        return;
    }
    i -= WFn;
    if (i < WFn) {       // w2 [L][C][FC][3] -> [L][3][C][FC]
        int c = i % FCn;
        int f = (i / FCn) % Cn;
        int ko = (i / (FCn * Cn)) % 3;
        int l = i / (3 * FCn * Cn);
        W2t[i] = __float2bfloat16(w2[(((size_t)(l * Cn + f)) * FCn + c) * 3 + ko]);
        return;
    }
    i -= WFn;
    if (i < (size_t)Ln * 16 * 96) {   // erk -> [L][16][96], rows 9..15 zero
        int d = i % 96, row = (i / 96) % 16, l = i / (96 * 16);
        float v = (row < 9) ? erk[((size_t)l * 9 + row) * 96 + d] : 0.f;
        ERKB[i] = __float2bfloat16(v);
        return;
    }
    i -= (size_t)Ln * 16 * 96;
    if (i < (size_t)Ln * 96 * 32) {   // erv -> [L][96][32] transposed, k 9..31 zero
        int k = i & 31, d = (i >> 5) % 96, l = i / (96 * 32);
        float v = (k < 9) ? erv[((size_t)l * 9 + k) * 96 + d] : 0.f;
        ERVB[i] = __float2bfloat16(v);
    }
}

// ---------------------------------------------------------------------------
// Input: X = x*mask (fp32, NCT) + XT = bf16 transposed [b][t][c]
__global__ __launch_bounds__(256) void cvt_in_k(
        const float* __restrict__ x, const float* __restrict__ mask,
        float* __restrict__ X, bf16* __restrict__ XT) {
    __shared__ float tile[Cn][33];
    const int tid = threadIdx.x, lane = tid & 31, w = tid >> 5;
    const int b = blockIdx.x >> 5;
    const int t0 = (blockIdx.x & 31) * 32;
    const float mk = mask[b * Tn + t0 + lane];
    for (int c = w; c < Cn; c += 8) {
        float v = x[((b * Cn + c) * Tn) + t0 + lane] * mk;
        X[((b * Cn + c) * Tn) + t0 + lane] = v;
        tile[c][lane] = v;
    }
    __syncthreads();
    for (int idx = tid; idx < 32 * Cn; idx += 256) {
        int tl = idx / Cn, c = idx % Cn;
        XT[((size_t)b * Tn + t0 + tl) * Cn + c] = __float2bfloat16(tile[c][tl]);
    }
}

// ---------------------------------------------------------------------------
// MFMA conv1d, LDS-staged, T14 async-STAGE (R4).
// MODE 0: fp32 NCT out (+bias, *mask if mask!=null)           [FFN2, R13]
// MODE 2: bf16 transposed [b][t][CO] out relu(+bias)*mask     [FFN1]
// MODE 4: QKV split: f<384 -> bf16 T (stride QKS) into Y0; else bf16 NCT Y1
//         (used only for layer 0; layers 1..5 get QKV from ln2_qkv)
template <int KS, int TT, int MODE, int NSP>
__global__ __launch_bounds__(256) void conv_mfma(
        const bf16* __restrict__ Xt, const bf16* __restrict__ W,
        const float* __restrict__ bias, const float* __restrict__ mask,
        void* __restrict__ Y0, void* __restrict__ Y1, int CIN, int CO) {
    constexpr int PAD = KS / 2;
    constexpr int NMB = TT / 16;
    constexpr int AR  = TT + KS - 1;        // A rows staged
    constexpr int RS  = 72;                 // padded row stride (bf16 cols)
    constexpr int NA  = (AR * 8 + 255) / 256;  // per-thread A short8 loads
    constexpr int NB  = KS * 2;                // per-thread B short8 loads
    __shared__ bf16 As[AR][RS];
    __shared__ bf16 Bs[KS][64][RS];

    const int tid = threadIdx.x;
    const int wv = tid >> 6, lane = tid & 63;
    const int m = lane & 15, kq = lane >> 4;
    const int b = blockIdx.z / NSP, ks = blockIdx.z % NSP;
    const int t0 = blockIdx.x * TT;
    const int f0 = blockIdx.y * 64;
    const int f = f0 + wv * 16 + m;

    const bf16* xb = Xt + (size_t)b * Tn * CIN;
    const size_t wko = (size_t)CO * CIN;

    int rA[NA], cA[NA];
    bool vA[NA];
#pragma unroll
    for (int i = 0; i < NA; ++i) {
        int s = tid + i * 256;
        rA[i] = s >> 3; cA[i] = (s & 7) * 8; vA[i] = (s < AR * 8);
    }
    int rB[NB], cB[NB], koB[NB];
#pragma unroll
    for (int i = 0; i < NB; ++i) {
        int s = tid + i * 256;          // always < KS*512
        koB[i] = s >> 9; rB[i] = (s >> 3) & 63; cB[i] = (s & 7) * 8;
    }

    short8 pa[NA], pb[NB];
    const int cbeg = ks * (CIN / NSP);
    const int cend = cbeg + CIN / NSP;

    auto issue = [&](int c0) {
#pragma unroll
        for (int i = 0; i < NA; ++i) {
            short8 v = {0, 0, 0, 0, 0, 0, 0, 0};
            if (vA[i]) {
                int gt = t0 + rA[i] - PAD;
                if (PAD == 0 || (unsigned)gt < (unsigned)Tn)
                    v = *(const short8*)(xb + (size_t)gt * CIN + c0 + cA[i]);
            }
            pa[i] = v;
        }
#pragma unroll
        for (int i = 0; i < NB; ++i)
            pb[i] = *(const short8*)(W + (size_t)koB[i] * wko +
                                     (size_t)(f0 + rB[i]) * CIN + c0 + cB[i]);
    };
    auto commit = [&]() {
#pragma unroll
        for (int i = 0; i < NA; ++i)
            if (vA[i]) *(short8*)&As[rA[i]][cA[i]] = pa[i];
#pragma unroll
        for (int i = 0; i < NB; ++i)
            *(short8*)&Bs[koB[i]][rB[i]][cB[i]] = pb[i];
    };

    f32x4 acc[NMB] = {};

    issue(cbeg);
    commit();
    __syncthreads();

    for (int c0 = cbeg; c0 < cend; c0 += 64) {
        const bool nxt = (c0 + 64 < cend);
        if (nxt) issue(c0 + 64);
#pragma unroll
        for (int kk = 0; kk < 2; ++kk)
#pragma unroll
            for (int ko = 0; ko < KS; ++ko) {
                short8 bfr = *(const short8*)&Bs[ko][wv * 16 + m][kk * 32 + kq * 8];
#pragma unroll
                for (int mb = 0; mb < NMB; ++mb) {
                    short8 afr = *(const short8*)&As[mb * 16 + m + ko][kk * 32 + kq * 8];
                    acc[mb] = __builtin_amdgcn_mfma_f32_16x16x32_bf16(afr, bfr, acc[mb], 0, 0, 0);
                }
            }
        if (nxt) {
            __syncthreads();   // all fragment reads of this chunk complete
            commit();
            __syncthreads();   // staged data visible
        }
    }

    const float bs = bias[f];
    if (MODE == 0) {
        float* Y = (float*)Y0 + ((size_t)b * CO + f) * Tn;
#pragma unroll
        for (int mb = 0; mb < NMB; ++mb) {
            int t = t0 + mb * 16 + kq * 4;
            float4 o;
            o.x = acc[mb][0] + bs; o.y = acc[mb][1] + bs;
            o.z = acc[mb][2] + bs; o.w = acc[mb][3] + bs;
            if (mask) {
                o.x *= mask[b * Tn + t];     o.y *= mask[b * Tn + t + 1];
                o.z *= mask[b * Tn + t + 2]; o.w *= mask[b * Tn + t + 3];
            }
            *(float4*)(Y + t) = o;
        }
    } else if (MODE == 2) {
        bf16* Y = (bf16*)Y0;
#pragma unroll
        for (int mb = 0; mb < NMB; ++mb)
#pragma unroll
            for (int r = 0; r < 4; ++r) {
                int t = t0 + mb * 16 + kq * 4 + r;
                float v = fmaxf(acc[mb][r] + bs, 0.f) * mask[b * Tn + t];
                Y[((size_t)b * Tn + t) * CO + f] = __float2bfloat16(v);
            }
    } else {  // MODE 4
        if (blockIdx.y < 6) {          // Q|K -> transposed, stride QKS
            bf16* Y = (bf16*)Y0;
#pragma unroll
            for (int mb = 0; mb < NMB; ++mb)
#pragma unroll
                for (int r = 0; r < 4; ++r) {
                    int t = t0 + mb * 16 + kq * 4 + r;
                    Y[((size_t)b * Tn + t) * QKS + f] = __float2bfloat16(acc[mb][r] + bs);
                }
        } else {                        // V -> bf16 NCT
            bf16* Y = (bf16*)Y1 + ((size_t)b * Cn + f - 384) * Tn;
#pragma unroll
            for (int mb = 0; mb < NMB; ++mb) {
                int t = t0 + mb * 16 + kq * 4;
                bf16 tmp[4];
#pragma unroll
                for (int r = 0; r < 4; ++r) tmp[r] = __float2bfloat16(acc[mb][r] + bs);
                *(uint2*)(Y + t) = *(uint2*)tmp;
            }
        }
    }
}

// ---------------------------------------------------------------------------
// R8: wo_ln_k at 512 threads / 8 waves (2 waves/SIMD). Waves map as
// 4 f-groups (48 ch) x 2 t-groups (16 rows); per-wave acc[3].
__global__ __launch_bounds__(512) void wo_ln_k(
        const bf16* __restrict__ Op, const float* __restrict__ Lp,
        const bf16* __restrict__ W, const float* __restrict__ bias,
        float* __restrict__ X, const float* __restrict__ G,
        const float* __restrict__ Bt, const float* __restrict__ mask,
        bf16* __restrict__ XT) {
    __shared__ bf16 As[32][72];       // combined attn out [t][c-chunk]
    __shared__ bf16 Bs[192][72];      // Wo panel [f][c-chunk]
    __shared__ float sm1[8][16];
    __shared__ float sm2[8][16];

    const int tid = threadIdx.x;
    const int wv = tid >> 6, lane = tid & 63;
    const int m = lane & 15, quad = lane >> 4;
    const int fg = wv & 3, tg = wv >> 2;
    const int b = blockIdx.x & 7;
    const int t0 = (blockIdx.x >> 3) * 32;

    const bool vA = (tid < 256);
    const int rA = tid >> 3, cA = (tid & 7) * 8;   // A: 32 rows x 8 short8
    short8 pa6[4]; float pl6[4];
    short8 pb[3];                                   // B: 1536 short8 / 512

    auto issue = [&](int c0) {
        if (vA) {
            int c = c0 + cA;
            int hh = (c >= 96) ? 1 : 0;
            int rid = (b * Hn + hh) * Tn + t0 + rA;
            int d0 = c - 96 * hh;
#pragma unroll
            for (int sp = 0; sp < 4; ++sp) {
                pa6[sp] = *(const short8*)(Op + ((size_t)sp * RN + rid) * 96 + d0);
                pl6[sp] = Lp[sp * RN + rid];
            }
        }
#pragma unroll
        for (int i = 0; i < 3; ++i) {
            int s = tid + i * 512;
            pb[i] = *(const short8*)(W + (size_t)(s >> 3) * Cn + c0 + (s & 7) * 8);
        }
    };
    auto commit = [&]() {
        if (vA) {
            float denom = pl6[0] + pl6[1] + pl6[2] + pl6[3];
            float inv = 1.f / fmaxf(denom, 1e-30f);
            bf16 tmp[8];
#pragma unroll
            for (int e = 0; e < 8; ++e) {
                float o = 0.f;
#pragma unroll
                for (int sp = 0; sp < 4; ++sp)
                    o += __bfloat162float(((const bf16*)&pa6[sp])[e]);
                tmp[e] = __float2bfloat16(o * inv);
            }
            *(short8*)&As[rA][cA] = *(const short8*)tmp;
        }
#pragma unroll
        for (int i = 0; i < 3; ++i) {
            int s = tid + i * 512;
            *(short8*)&Bs[s >> 3][(s & 7) * 8] = pb[i];
        }
    };

    f32x4 acc[3] = {};

    issue(0);
    commit();
    __syncthreads();
    for (int c0 = 0; c0 < Cn; c0 += 64) {
        const bool nxt = (c0 + 64 < Cn);
        if (nxt) issue(c0 + 64);
#pragma unroll
        for (int kk = 0; kk < 2; ++kk) {
            short8 afr = *(const short8*)&As[tg * 16 + m][kk * 32 + quad * 8];
#pragma unroll
            for (int fb = 0; fb < 3; ++fb) {
                short8 bfr = *(const short8*)&Bs[fg * 48 + fb * 16 + m][kk * 32 + quad * 8];
                acc[fb] = __builtin_amdgcn_mfma_f32_16x16x32_bf16(afr, bfr, acc[fb], 0, 0, 0);
            }
        }
        if (nxt) {
            __syncthreads();
            commit();
            __syncthreads();
        }
    }

    // bias + residual; per-t LN stats over this lane's 3 channels
    const int tq = t0 + tg * 16 + quad * 4;
    float s1[4] = {}, s2[4] = {};
#pragma unroll
    for (int fb = 0; fb < 3; ++fb) {
        const int f = fg * 48 + fb * 16 + m;
        const float bsv = bias[f];
        float4 xv = *(const float4*)(X + ((size_t)(b * Cn + f)) * Tn + tq);
        acc[fb][0] += bsv + xv.x;
        acc[fb][1] += bsv + xv.y;
        acc[fb][2] += bsv + xv.z;
        acc[fb][3] += bsv + xv.w;
#pragma unroll
        for (int r = 0; r < 4; ++r) {
            float v = acc[fb][r];
            s1[r] += v;
            s2[r] += v * v;
        }
    }
#pragma unroll
    for (int r = 0; r < 4; ++r)
#pragma unroll
        for (int mk = 1; mk < 16; mk <<= 1) {
            s1[r] += __shfl_xor(s1[r], mk);
            s2[r] += __shfl_xor(s2[r], mk);
        }
    if (m == 0) {
#pragma unroll
        for (int r = 0; r < 4; ++r) {
            sm1[wv][quad * 4 + r] = s1[r];
            sm2[wv][quad * 4 + r] = s2[r];
        }
    }
    __syncthreads();
    float mean[4], rsv[4];
    float4 mk4 = *(const float4*)(mask + b * Tn + tq);
    float mtv[4] = {mk4.x, mk4.y, mk4.z, mk4.w};
#pragma unroll
    for (int r = 0; r < 4; ++r) {
        int tt = quad * 4 + r;
        float a = sm1[tg * 4 + 0][tt] + sm1[tg * 4 + 1][tt] +
                  sm1[tg * 4 + 2][tt] + sm1[tg * 4 + 3][tt];
        float q = sm2[tg * 4 + 0][tt] + sm2[tg * 4 + 1][tt] +
                  sm2[tg * 4 + 2][tt] + sm2[tg * 4 + 3][tt];
        float mn = a / Cn;
        mean[r] = mn;
        rsv[r] = rsqrtf(q / Cn - mn * mn + 1e-5f);
    }
#pragma unroll
    for (int fb = 0; fb < 3; ++fb) {
        const int f = fg * 48 + fb * 16 + m;
        const float gv = G[f], bv = Bt[f];
        float y[4];
#pragma unroll
        for (int r = 0; r < 4; ++r)
            y[r] = (acc[fb][r] - mean[r]) * rsv[r] * gv + bv;
        float4 xo;
        xo.x = y[0]; xo.y = y[1]; xo.z = y[2]; xo.w = y[3];
        *(float4*)(X + ((size_t)(b * Cn + f)) * Tn + tq) = xo;
#pragma unroll
        for (int r = 0; r < 4; ++r)
            XT[((size_t)b * Tn + tq + r) * Cn + f] =
                __float2bfloat16(y[r] * mtv[r]);
    }
}

// ---------------------------------------------------------------------------
// R13: slim ln2_qkv — phase 1 ELEMENTWISE (FFN2 conv split back out to the
// proven many-block conv_mfma, which writes Yb = (conv+bias)*mask fp32):
// v = X + Yb, channel-LN2, write X (or OUT on last layer). Phase 2: the
// NEXT layer's QKV 1x1 conv, verbatim R10 (LDS-staged Bq, depth-1).
// QKV weight prefetch issued at kernel entry hides under phase 1.
// 768 threads, grid 256; LDS ~97 KB -> 1 block/CU, 3 waves/SIMD.
__global__ __launch_bounds__(768) void ln2_qkv(
        const float* __restrict__ Yb, float* __restrict__ X,
        const float* __restrict__ G, const float* __restrict__ Bt,
        const float* __restrict__ mask,
        const bf16* __restrict__ Wqn, const float* __restrict__ bqn,
        bf16* __restrict__ QKT, bf16* __restrict__ Vb,
        float* __restrict__ OUT) {
    __shared__ bf16 Bq[576][72];       // Wqkv panel (phase 2 B)
    __shared__ bf16 Ys[32][200];       // LN2 output tile [t][c] (phase 2 A)
    __shared__ float sm1[12][16];
    __shared__ float sm2[12][16];

    const int tid = threadIdx.x;
    const int wv = tid >> 6, lane = tid & 63;
    const int m = lane & 15, quad = lane >> 4;
    const int fg = wv % 6, tg = wv / 6;      // 6 f-groups x 2 t-groups
    const int b = blockIdx.x & 7;
    const int t0 = (blockIdx.x >> 3) * 32;
    const int tq = t0 + tg * 16 + quad * 4;

    // phase-2 weight prefetch (hidden under phase 1)
    short8 pbq[6];
    auto issueQ = [&](int c0) {
#pragma unroll
        for (int i = 0; i < 6; ++i) {
            int s = tid + i * 768;           // < 4608 = 576*8
            pbq[i] = *(const short8*)(Wqn + (size_t)(s >> 3) * Cn + c0 + (s & 7) * 8);
        }
    };
    auto commitQ = [&]() {
#pragma unroll
        for (int i = 0; i < 6; ++i) {
            int s = tid + i * 768;
            *(short8*)&Bq[s >> 3][(s & 7) * 8] = pbq[i];
        }
    };
    const bool doQ = (OUT == nullptr);
    if (doQ) issueQ(0);

    // phase 1: v = X + Yb (Yb already biased+masked); LN stats
    float4 mk4 = *(const float4*)(mask + b * Tn + tq);
    float mtv[4] = {mk4.x, mk4.y, mk4.z, mk4.w};
    f32x4 acc[2];
    float s1[4] = {}, s2[4] = {};
#pragma unroll
    for (int fb = 0; fb < 2; ++fb) {
        const int f = fg * 32 + fb * 16 + m;
        size_t i = ((size_t)(b * Cn + f)) * Tn + tq;
        float4 yv = *(const float4*)(Yb + i);
        float4 xv = *(const float4*)(X + i);
        acc[fb][0] = xv.x + yv.x;
        acc[fb][1] = xv.y + yv.y;
        acc[fb][2] = xv.z + yv.z;
        acc[fb][3] = xv.w + yv.w;
#pragma unroll
        for (int r = 0; r < 4; ++r) {
            float v = acc[fb][r];
            s1[r] += v;
            s2[r] += v * v;
        }
    }
#pragma unroll
    for (int r = 0; r < 4; ++r)
#pragma unroll
        for (int mk = 1; mk < 16; mk <<= 1) {
            s1[r] += __shfl_xor(s1[r], mk);
            s2[r] += __shfl_xor(s2[r], mk);
        }
    if (m == 0) {
#pragma unroll
        for (int r = 0; r < 4; ++r) {
            sm1[wv][quad * 4 + r] = s1[r];
            sm2[wv][quad * 4 + r] = s2[r];
        }
    }
    __syncthreads();
    float mean[4], rsv[4];
#pragma unroll
    for (int r = 0; r < 4; ++r) {
        int tt = quad * 4 + r;
        float a = 0.f, q = 0.f;
#pragma unroll
        for (int j = 0; j < 6; ++j) {
            a += sm1[tg * 6 + j][tt];
            q += sm2[tg * 6 + j][tt];
        }
        float mn = a / Cn;
        mean[r] = mn;
        rsv[r] = rsqrtf(q / Cn - mn * mn + 1e-5f);
    }

    float y3[2][4];
#pragma unroll
    for (int fb = 0; fb < 2; ++fb) {
        const int f = fg * 32 + fb * 16 + m;
        const float gv = G[f], bv = Bt[f];
#pragma unroll
        for (int r = 0; r < 4; ++r)
            y3[fb][r] = (acc[fb][r] - mean[r]) * rsv[r] * gv + bv;
    }

    if (OUT) {      // final layer: OUT = LN(...)*mask, NCT fp32; no QKV
#pragma unroll
        for (int fb = 0; fb < 2; ++fb) {
            const int f = fg * 32 + fb * 16 + m;
            float4 xo;
            xo.x = y3[fb][0] * mtv[0]; xo.y = y3[fb][1] * mtv[1];
            xo.z = y3[fb][2] * mtv[2]; xo.w = y3[fb][3] * mtv[3];
            *(float4*)(OUT + ((size_t)(b * Cn + f)) * Tn + tq) = xo;
        }
        return;
    }

    // write X (residual stream for next layer's wo_ln_k)
#pragma unroll
    for (int fb = 0; fb < 2; ++fb) {
        const int f = fg * 32 + fb * 16 + m;
        float4 xo;
        xo.x = y3[fb][0]; xo.y = y3[fb][1]; xo.z = y3[fb][2]; xo.w = y3[fb][3];
        *(float4*)(X + ((size_t)(b * Cn + f)) * Tn + tq) = xo;
    }

    // ---- phase 2: QKV 1x1 conv for the NEXT layer (R10 structure) ----
    // drop y (unmasked, matching old XT semantics) into the LDS A-tile
#pragma unroll
    for (int fb = 0; fb < 2; ++fb) {
        const int f = fg * 32 + fb * 16 + m;
#pragma unroll
        for (int r = 0; r < 4; ++r)
            Ys[tg * 16 + quad * 4 + r][f] = __float2bfloat16(y3[fb][r]);
    }
    commitQ();
    __syncthreads();     // Ys + Bq chunk 0 visible

    f32x4 acc2[6] = {};
    for (int c0 = 0; c0 < Cn; c0 += 64) {
        const bool nxt = (c0 + 64 < Cn);
        if (nxt) issueQ(c0 + 64);
#pragma unroll
        for (int kk = 0; kk < 2; ++kk) {
            short8 afr = *(const short8*)&Ys[tg * 16 + m][c0 + kk * 32 + quad * 8];
#pragma unroll
            for (int fb = 0; fb < 6; ++fb) {
                short8 bfr = *(const short8*)&Bq[fg * 96 + fb * 16 + m][kk * 32 + quad * 8];
                acc2[fb] = __builtin_amdgcn_mfma_f32_16x16x32_bf16(afr, bfr, acc2[fb], 0, 0, 0);
            }
        }
        if (nxt) {
            __syncthreads();
            commitQ();
            __syncthreads();
        }
    }

    // epilogue: QKT transposed (f<384) / Vb NCT (f>=384), bias added
#pragma unroll
    for (int fb = 0; fb < 6; ++fb) {
        const int f = fg * 96 + fb * 16 + m;
        const float bsv = bqn[f];
        if (f < 384) {
#pragma unroll
            for (int r = 0; r < 4; ++r)
                QKT[((size_t)b * Tn + tq + r) * QKS + f] =
                    __float2bfloat16(acc2[fb][r] + bsv);
        } else {
            bf16 tmp[4];
#pragma unroll
            for (int r = 0; r < 4; ++r) tmp[r] = __float2bfloat16(acc2[fb][r] + bsv);
            *(uint2*)(Vb + ((size_t)b * Cn + f - 384) * Tn + tq) = *(uint2*)tmp;
        }
    }
}

// ---------------------------------------------------------------------------
// MFMA flash attention. R8: 8 waves / QBLK=128 per block (512 threads,
// grid 512). XCD swizzle (R2), T14 async-STAGE (R2), rel-V via MFMA (R3),
// ones-MFMA rowsum + gating + setprio (R5). FIXED-MAX softmax.
// Writes UNNORMALIZED partials: Op bf16 [sp][rid][96], Lp fp32 [sp][rid].
__global__ __launch_bounds__(512) void attn_mfma(
        const bf16* __restrict__ QK, const bf16* __restrict__ V,
        const float* __restrict__ mask, const bf16* __restrict__ erkb,
        const bf16* __restrict__ ervb, bf16* __restrict__ Op,
        float* __restrict__ Lp, int layer) {
    __shared__ bf16 Ks[64][100];      // K chunk [s][d]
    __shared__ bf16 Vs[96][68];       // V chunk [d][s]
    __shared__ float rq[8][16][17];   // per-wave rel-K band: [m][dd]
    __shared__ bf16 pT[8][16][68];    // per-wave P: [m][s]
    __shared__ bf16 pdg[8][16][16];   // per-wave rel-V band: [m][dd], 9..15 zero
    // LDS total: 56064 B -> 2 blocks/CU

    const int tid = threadIdx.x, wv = tid >> 6, lane = tid & 63;
    const int col = lane & 15, quad = lane >> 4;
    // XCD-bijective swizzle (512 = 8 XCD x 64)
    const int w = (blockIdx.x & 7) * 64 + (blockIdx.x >> 3);
    const int t0 = (w & 7) * 128;
    const int yz = w >> 3;
    const int h = yz & 1;
    const int z = yz >> 1;
    const int b = z >> 2, sp = z & 3;
    const int hd = h * DKn;
    const int t0w = t0 + wv * 16;

    *(uint2*)&pdg[wv][col][quad * 4] = (uint2){0, 0};

    const bool g2 = (tid < 256);
    int rK[2], cK[2], rV[2], cV[2];
    {
        int s = tid;
        rK[0] = s / 12; cK[0] = (s % 12) * 8;   // 64 rows x 96 cols
        rV[0] = s >> 3; cV[0] = (s & 7) * 8;    // 96 rows x 64 cols
        s = tid + 512;
        rK[1] = s / 12; cK[1] = (s % 12) * 8;   // valid only if g2
        rV[1] = s >> 3; cV[1] = (s & 7) * 8;
    }
    const bf16* kbase = QK + (size_t)b * Tn * QKS + 192 + hd;
    const bf16* vbase = V + ((size_t)b * Cn + hd) * Tn;

    short8 kst[2], vst[2];
    const int sbeg = sp * (Tn / NSPLIT);
    const int send = sbeg + Tn / NSPLIT;

    kst[0] = *(const short8*)(kbase + (size_t)(sbeg + rK[0]) * QKS + cK[0]);
    vst[0] = *(const short8*)(vbase + (size_t)rV[0] * Tn + sbeg + cV[0]);
    if (g2) {
        kst[1] = *(const short8*)(kbase + (size_t)(sbeg + rK[1]) * QKS + cK[1]);
        vst[1] = *(const short8*)(vbase + (size_t)rV[1] * Tn + sbeg + cV[1]);
    }

    short8 aq[3];
    {
        const bf16* qrow = QK + ((size_t)b * Tn + t0w + col) * QKS + hd + quad * 8;
#pragma unroll
        for (int kd = 0; kd < 3; ++kd) aq[kd] = *(const short8*)(qrow + kd * 32);
    }
    {
        const bf16* erow = erkb + ((size_t)layer * 16 + col) * 96 + quad * 8;
        f32x4 R = {};
#pragma unroll
        for (int kd = 0; kd < 3; ++kd) {
            short8 be = *(const short8*)(erow + kd * 32);
            R = __builtin_amdgcn_mfma_f32_16x16x32_bf16(aq[kd], be, R, 0, 0, 0);
        }
#pragma unroll
        for (int r = 0; r < 4; ++r) rq[wv][quad * 4 + r][col] = R[r];
    }
    float mtv[4];
#pragma unroll
    for (int r = 0; r < 4; ++r) mtv[r] = mask[b * Tn + t0w + quad * 4 + r];
    const bool qok = __all(mtv[0] != 0.f && mtv[1] != 0.f &&
                           mtv[2] != 0.f && mtv[3] != 0.f);
    int okbits = 0;
    if (qok) {
#pragma unroll
        for (int ch = 0; ch < 4; ++ch) {
            int sc = b * Tn + sbeg + ch * 64 + col;
            float a0 = mask[sc], a1 = mask[sc + 16], a2 = mask[sc + 32], a3 = mask[sc + 48];
            if (__all(a0 != 0.f && a1 != 0.f && a2 != 0.f && a3 != 0.f))
                okbits |= 1 << ch;
        }
    }

    *(short8*)&Ks[rK[0]][cK[0]] = kst[0];
    *(short8*)&Vs[rV[0]][cV[0]] = vst[0];
    if (g2) {
        *(short8*)&Ks[rK[1]][cK[1]] = kst[1];
        *(short8*)&Vs[rV[1]][cV[1]] = vst[1];
    }
    __syncthreads();

    f32x4 O[6] = {};
    f32x4 Osum = {};
    short8 ones;
#pragma unroll
    for (int j = 0; j < 8; ++j) ones[j] = (short)0x3F80;   // bf16 1.0

    for (int s0 = sbeg; s0 < send; s0 += 64) {
        const bool nxt = (s0 + 64 < send);
        if (nxt) {
            kst[0] = *(const short8*)(kbase + (size_t)(s0 + 64 + rK[0]) * QKS + cK[0]);
            vst[0] = *(const short8*)(vbase + (size_t)rV[0] * Tn + s0 + 64 + cV[0]);
            if (g2) {
                kst[1] = *(const short8*)(kbase + (size_t)(s0 + 64 + rK[1]) * QKS + cK[1]);
                vst[1] = *(const short8*)(vbase + (size_t)rV[1] * Tn + s0 + 64 + cV[1]);
            }
        }

        f32x4 S[4] = {};
        __builtin_amdgcn_s_setprio(1);
#pragma unroll
        for (int nb = 0; nb < 4; ++nb)
#pragma unroll
            for (int kd = 0; kd < 3; ++kd) {
                short8 bkf = *(const short8*)&Ks[16 * nb + col][kd * 32 + quad * 8];
                S[nb] = __builtin_amdgcn_mfma_f32_16x16x32_bf16(aq[kd], bkf, S[nb], 0, 0, 0);
            }
        __builtin_amdgcn_s_setprio(0);

        const bool diag = (s0 <= t0w + 15 + WINn) && (s0 + 63 >= t0w - WINn);
        if (diag) {
#pragma unroll
            for (int nb = 0; nb < 4; ++nb) {
                const int sg = s0 + 16 * nb + col;
#pragma unroll
                for (int r = 0; r < 4; ++r) {
                    int dd = sg - (t0w + quad * 4 + r) + WINn;
                    if ((unsigned)dd <= 2u * WINn) S[nb][r] += rq[wv][quad * 4 + r][dd];
                }
            }
        }
        if (!((okbits >> ((s0 - sbeg) >> 6)) & 1)) {
#pragma unroll
            for (int nb = 0; nb < 4; ++nb) {
                const float msv = mask[b * Tn + s0 + 16 * nb + col];
#pragma unroll
                for (int r = 0; r < 4; ++r)
                    if (msv * mtv[r] == 0.f) S[nb][r] = -1e4f;
            }
        }

        if (diag) {
#pragma unroll
            for (int nb = 0; nb < 4; ++nb) {
                const int sg = s0 + 16 * nb + col;
#pragma unroll
                for (int r = 0; r < 4; ++r) {
                    bf16 pb_ = __float2bfloat16(__expf(S[nb][r]));
                    pT[wv][quad * 4 + r][16 * nb + col] = pb_;
                    int dd = sg - (t0w + quad * 4 + r) + WINn;
                    if ((unsigned)dd <= 2u * WINn) pdg[wv][quad * 4 + r][dd] = pb_;
                }
            }
        } else {
#pragma unroll
            for (int nb = 0; nb < 4; ++nb)
#pragma unroll
                for (int r = 0; r < 4; ++r)
                    pT[wv][quad * 4 + r][16 * nb + col] =
                        __float2bfloat16(__expf(S[nb][r]));
        }

        short8 aP[2];
#pragma unroll
        for (int kk = 0; kk < 2; ++kk)
            aP[kk] = *(const short8*)&pT[wv][col][kk * 32 + quad * 8];
        __builtin_amdgcn_s_setprio(1);
#pragma unroll
        for (int nd = 0; nd < 6; ++nd)
#pragma unroll
            for (int kk = 0; kk < 2; ++kk) {
                short8 bvf = *(const short8*)&Vs[16 * nd + col][kk * 32 + quad * 8];
                O[nd] = __builtin_amdgcn_mfma_f32_16x16x32_bf16(aP[kk], bvf, O[nd], 0, 0, 0);
            }
#pragma unroll
        for (int kk = 0; kk < 2; ++kk)
            Osum = __builtin_amdgcn_mfma_f32_16x16x32_bf16(aP[kk], ones, Osum, 0, 0, 0);
        __builtin_amdgcn_s_setprio(0);

        __syncthreads();
        if (nxt) {
            *(short8*)&Ks[rK[0]][cK[0]] = kst[0];
            *(short8*)&Vs[rV[0]][cV[0]] = vst[0];
            if (g2) {
                *(short8*)&Ks[rK[1]][cK[1]] = kst[1];
                *(short8*)&Vs[rV[1]][cV[1]] = vst[1];
            }
            __syncthreads();
        }
    }

    // rel-V band contribution: O += pdg(16x16, k 9..15 zero) . ERVB(k x 96)
    {
        short8 ad = {0, 0, 0, 0, 0, 0, 0, 0};
        if (quad < 2) ad = *(const short8*)&pdg[wv][col][quad * 8];
        const bf16* eb = ervb + (size_t)layer * 96 * 32 + (size_t)col * 32 + quad * 8;
#pragma unroll
        for (int nd = 0; nd < 6; ++nd) {
            short8 bd = *(const short8*)(eb + (size_t)nd * 16 * 32);
            O[nd] = __builtin_amdgcn_mfma_f32_16x16x32_bf16(ad, bd, O[nd], 0, 0, 0);
        }
    }

    // epilogue: write unnormalized partials (Lp row-sums come from Osum)
    const int rbase = (b * Hn + h) * Tn + t0w;
#pragma unroll
    for (int r = 0; r < 4; ++r) {
        const int rid = rbase + quad * 4 + r;
        bf16* dst = Op + ((size_t)sp * RN + rid) * 96 + col;
#pragma unroll
        for (int nd = 0; nd < 6; ++nd)
            dst[16 * nd] = __float2bfloat16(O[nd][r]);
        if (col == 0) Lp[sp * RN + rid] = Osum[r];
    }
}

// ---------------------------------------------------------------------------
extern "C" void kernel_launch(void* const* d_in, const int* in_sizes, int n_in,
                              void* d_out, int out_size, void* d_ws, size_t ws_size,
                              hipStream_t stream) {
    const float* x    = (const float*)d_in[0];
    const float* mask = (const float*)d_in[1];
    const float* Wq   = (const float*)d_in[2];
    const float* bq   = (const float*)d_in[3];
    const float* Wk   = (const float*)d_in[4];
    const float* bk   = (const float*)d_in[5];
    const float* Wv   = (const float*)d_in[6];
    const float* bv   = (const float*)d_in[7];
    const float* Wo   = (const float*)d_in[8];
    const float* bo   = (const float*)d_in[9];
    const float* erk  = (const float*)d_in[10];
    const float* erv  = (const float*)d_in[11];
    const float* ln1g = (const float*)d_in[12];
    const float* ln1b = (const float*)d_in[13];
    const float* w1   = (const float*)d_in[14];
    const float* b1   = (const float*)d_in[15];
    const float* w2   = (const float*)d_in[16];
    const float* b2   = (const float*)d_in[17];
    const float* ln2g = (const float*)d_in[18];
    const float* ln2b = (const float*)d_in[19];

    const size_t N = (size_t)Bn * Cn * Tn;         // 1,572,864
    const int WC = Ln * Cn * Cn;                   // 221,184
    const size_t WF = (size_t)Ln * 3 * FCn * Cn;   // 2,654,208
    const size_t WQKV = (size_t)Ln * 576 * Cn;     // 663,552
    const size_t NSCR = (size_t)Bn * Tn * FCn;     // 6,291,456 == NSPLIT*RN*96

    float* X    = (float*)d_ws;
    float* Yb   = X + N;                           // FFN2 output (fp32 NCT)
    float* bqkv = Yb + N;                          // L*576 floats
    float* Lp   = bqkv + Ln * 576;                 // NSPLIT*RN floats
    bf16* p16 = (bf16*)(Lp + (size_t)NSPLIT * RN);
    bf16* XT   = p16; p16 += N;
    bf16* QKT  = p16; p16 += (size_t)Bn * Tn * QKS;  // 2N bf16
    bf16* Vb   = p16; p16 += N;
    bf16* AT   = p16; p16 += N;      // (unused; kept for layout)
    bf16* SCR  = p16; p16 += NSCR;   // shared: attn O-partials <-> FFN hidden
    bf16* Wqkv = p16; p16 += WQKV;
    bf16* Wob  = p16; p16 += WC;
    bf16* W1t  = p16; p16 += WF;
    bf16* W2t  = p16; p16 += WF;
    bf16* ERKB = p16; p16 += Ln * 16 * 96;
    bf16* ERVB = p16; p16 += Ln * 96 * 32;
    (void)AT;

    const float qscale = 0.10206207261596575f;  // 1/sqrt(96)

    // one-time transforms: single fused dispatch
    const size_t nprep = WQKV + Ln * 576 + WC + 2 * WF +
                         (size_t)Ln * 16 * 96 + (size_t)Ln * 96 * 32;
    prep_all<<<(int)((nprep + 255) / 256), 256, 0, stream>>>(
        Wq, Wk, Wv, bq, bk, bv, Wo, w1, w2, erk, erv,
        Wqkv, bqkv, Wob, W1t, W2t, ERKB, ERVB, qscale);
    cvt_in_k<<<Bn * 32, 256, 0, stream>>>(x, mask, X, XT);

    // layer 0's QKV from XT (standalone conv); layers 1..5 get QKV fused
    // into the previous layer's ln2_qkv.
    conv_mfma<1, 128, 4, 1><<<dim3(Tn / 128, 9, Bn), 256, 0, stream>>>(
        XT, Wqkv, bqkv, nullptr, QKT, Vb, Cn, 576);

    for (int l = 0; l < Ln; ++l) {
        attn_mfma<<<dim3(512), 512, 0, stream>>>(
            QKT, Vb, mask, ERKB, ERVB, SCR, Lp, l);
        // fused: split-combine + Wo conv + residual + LN1 + X/XT write
        wo_ln_k<<<256, 512, 0, stream>>>(
            SCR, Lp, Wob + (size_t)l * Cn * Cn, bo + l * Cn,
            X, ln1g + l * Cn, ln1b + l * Cn, mask, XT);
        conv_mfma<3, 128, 2, 1><<<dim3(Tn / 128, FCn / 64, Bn), 256, 0, stream>>>(
            XT, W1t + (size_t)l * 3 * FCn * Cn, b1 + l * FCn, mask, SCR, nullptr, Cn, FCn);
        // FFN2 conv: full-K many-block (384 blocks), Yb = (conv+bias)*mask
        conv_mfma<3, 64, 0, 1><<<dim3(Tn / 64, 3, Bn), 256, 0, stream>>>(
            SCR, W2t + (size_t)l * 3 * Cn * FCn, b2 + l * Cn, mask, Yb, nullptr, FCn, Cn);
        // slim: residual + LN2 + next layer's QKV (or OUT on last layer)
        const bool last = (l == Ln - 1);
        ln2_qkv<<<256, 768, 0, stream>>>(
            Yb, X, ln2g + l * Cn, ln2b + l * Cn, mask,
            last ? nullptr : (Wqkv + (size_t)(l + 1) * 576 * Cn),
            last ? nullptr : (bqkv + (l + 1) * 576),
            QKT, Vb,
            last ? (float*)d_out : nullptr);
    }
}

// Round 14
// 588.845 us; speedup vs baseline: 1.3699x; 1.0430x over previous
//
#include <hip/hip_runtime.h>
#include <hip/hip_bf16.h>

// Problem constants
constexpr int Bn  = 8;
constexpr int Cn  = 192;   // hidden channels
constexpr int Tn  = 1024;  // sequence length
constexpr int Hn  = 2;     // heads
constexpr int DKn = 96;    // head dim
constexpr int FCn = 768;   // filter channels
constexpr int Ln  = 6;     // layers
constexpr int WINn = 4;    // rel-attn window
constexpr int QKS = 384;   // QK transposed row stride (Q|K concat)
constexpr int NSPLIT = 4;  // attention s-split (flash-decoding)
constexpr int RN  = Bn * Hn * Tn;  // 16384 attention rows

typedef __hip_bfloat16 bf16;
typedef __attribute__((ext_vector_type(8))) short short8;
typedef __attribute__((ext_vector_type(4))) float f32x4;

// ---------------------------------------------------------------------------
// One-time weight transforms in a single grid-stride kernel (R6).
__global__ void prep_all(
        const float* __restrict__ Wq, const float* __restrict__ Wk,
        const float* __restrict__ Wv, const float* __restrict__ bq,
        const float* __restrict__ bk, const float* __restrict__ bv,
        const float* __restrict__ Wo, const float* __restrict__ w1,
        const float* __restrict__ w2, const float* __restrict__ erk,
        const float* __restrict__ erv,
        bf16* __restrict__ Wqkv, float* __restrict__ bqkv,
        bf16* __restrict__ Wob, bf16* __restrict__ W1t, bf16* __restrict__ W2t,
        bf16* __restrict__ ERKB, bf16* __restrict__ ERVB, float qscale) {
    size_t i = (size_t)blockIdx.x * 256 + threadIdx.x;
    const size_t nW  = (size_t)Ln * 576 * Cn;     // 663,552
    const size_t nB  = (size_t)Ln * 576;
    const size_t WCn = (size_t)Ln * Cn * Cn;      // 221,184
    const size_t WFn = (size_t)Ln * 3 * FCn * Cn; // 2,654,208
    if (i < nW) {        // fused QKV weight (qscale folded into Q)
        int c = i % Cn, f = (i / Cn) % 576, l = i / (Cn * 576);
        float v;
        if (f < 192)      v = Wq[((size_t)l * Cn + f) * Cn + c] * qscale;
        else if (f < 384) v = Wk[((size_t)l * Cn + f - 192) * Cn + c];
        else              v = Wv[((size_t)l * Cn + f - 384) * Cn + c];
        Wqkv[i] = __float2bfloat16(v);
        return;
    }
    i -= nW;
    if (i < nB) {        // fused QKV bias
        int f = i % 576, l = i / 576;
        float v;
        if (f < 192)      v = bq[l * Cn + f] * qscale;
        else if (f < 384) v = bk[l * Cn + f - 192];
        else              v = bv[l * Cn + f - 384];
        bqkv[i] = v;
        return;
    }
    i -= nB;
    if (i < WCn) {       // Wo cast
        Wob[i] = __float2bfloat16(Wo[i]);
        return;
    }
    i -= WCn;
    if (i < WFn) {       // w1 [L][FC][C][3] -> [L][3][FC][C]
        int c = i % Cn;
        int f = (i / Cn) % FCn;
        int ko = (i / (Cn * FCn)) % 3;
        int l = i / (3 * Cn * FCn);
        W1t[i] = __float2bfloat16(w1[(((size_t)(l * FCn + f)) * Cn + c) * 3 + ko]);
        return;
    }
    i -= WFn;
    if (i < WFn) {       // w2 [L][C][FC][3] -> [L][3][C][FC]
        int c = i % FCn;
        int f = (i / FCn) % Cn;
        int ko = (i / (FCn * Cn)) % 3;
        int l = i / (3 * FCn * Cn);
        W2t[i] = __float2bfloat16(w2[(((size_t)(l * Cn + f)) * FCn + c) * 3 + ko]);
        return;
    }
    i -= WFn;
    if (i < (size_t)Ln * 16 * 96) {   // erk -> [L][16][96], rows 9..15 zero
        int d = i % 96, row = (i / 96) % 16, l = i / (96 * 16);
        float v = (row < 9) ? erk[((size_t)l * 9 + row) * 96 + d] : 0.f;
        ERKB[i] = __float2bfloat16(v);
        return;
    }
    i -= (size_t)Ln * 16 * 96;
    if (i < (size_t)Ln * 96 * 32) {   // erv -> [L][96][32] transposed, k 9..31 zero
        int k = i & 31, d = (i >> 5) % 96, l = i / (96 * 32);
        float v = (k < 9) ? erv[((size_t)l * 9 + k) * 96 + d] : 0.f;
        ERVB[i] = __float2bfloat16(v);
    }
}

// ---------------------------------------------------------------------------
// Input: X = x*mask (fp32, NCT) + XT = bf16 transposed [b][t][c]
__global__ __launch_bounds__(256) void cvt_in_k(
        const float* __restrict__ x, const float* __restrict__ mask,
        float* __restrict__ X, bf16* __restrict__ XT) {
    __shared__ float tile[Cn][33];
    const int tid = threadIdx.x, lane = tid & 31, w = tid >> 5;
    const int b = blockIdx.x >> 5;
    const int t0 = (blockIdx.x & 31) * 32;
    const float mk = mask[b * Tn + t0 + lane];
    for (int c = w; c < Cn; c += 8) {
        float v = x[((b * Cn + c) * Tn) + t0 + lane] * mk;
        X[((b * Cn + c) * Tn) + t0 + lane] = v;
        tile[c][lane] = v;
    }
    __syncthreads();
    for (int idx = tid; idx < 32 * Cn; idx += 256) {
        int tl = idx / Cn, c = idx % Cn;
        XT[((size_t)b * Tn + t0 + tl) * Cn + c] = __float2bfloat16(tile[c][tl]);
    }
}

// ---------------------------------------------------------------------------
// MFMA conv1d, LDS-staged, TT=128 for K-heavy convs, T14 async-STAGE (R4).
// MODE 2: bf16 transposed [b][t][CO] out relu(+bias)*mask   [FFN1]
// MODE 4: QKV split: f<384 -> bf16 T (stride QKS) into Y0; else bf16 NCT Y1
//         (used only for layer 0; layers 1..5 get QKV from ffn2_ln_qkv)
template <int KS, int TT, int MODE, int NSP>
__global__ __launch_bounds__(256) void conv_mfma(
        const bf16* __restrict__ Xt, const bf16* __restrict__ W,
        const float* __restrict__ bias, const float* __restrict__ mask,
        void* __restrict__ Y0, void* __restrict__ Y1, int CIN, int CO) {
    constexpr int PAD = KS / 2;
    constexpr int NMB = TT / 16;
    constexpr int AR  = TT + KS - 1;        // A rows staged
    constexpr int RS  = 72;                 // padded row stride (bf16 cols)
    constexpr int NA  = (AR * 8 + 255) / 256;  // per-thread A short8 loads
    constexpr int NB  = KS * 2;                // per-thread B short8 loads
    __shared__ bf16 As[AR][RS];
    __shared__ bf16 Bs[KS][64][RS];

    const int tid = threadIdx.x;
    const int wv = tid >> 6, lane = tid & 63;
    const int m = lane & 15, kq = lane >> 4;
    const int b = blockIdx.z / NSP, ks = blockIdx.z % NSP;
    const int t0 = blockIdx.x * TT;
    const int f0 = blockIdx.y * 64;
    const int f = f0 + wv * 16 + m;

    const bf16* xb = Xt + (size_t)b * Tn * CIN;
    const size_t wko = (size_t)CO * CIN;

    int rA[NA], cA[NA];
    bool vA[NA];
#pragma unroll
    for (int i = 0; i < NA; ++i) {
        int s = tid + i * 256;
        rA[i] = s >> 3; cA[i] = (s & 7) * 8; vA[i] = (s < AR * 8);
    }
    int rB[NB], cB[NB], koB[NB];
#pragma unroll
    for (int i = 0; i < NB; ++i) {
        int s = tid + i * 256;          // always < KS*512
        koB[i] = s >> 9; rB[i] = (s >> 3) & 63; cB[i] = (s & 7) * 8;
    }

    short8 pa[NA], pb[NB];
    const int cbeg = ks * (CIN / NSP);
    const int cend = cbeg + CIN / NSP;

    auto issue = [&](int c0) {
#pragma unroll
        for (int i = 0; i < NA; ++i) {
            short8 v = {0, 0, 0, 0, 0, 0, 0, 0};
            if (vA[i]) {
                int gt = t0 + rA[i] - PAD;
                if (PAD == 0 || (unsigned)gt < (unsigned)Tn)
                    v = *(const short8*)(xb + (size_t)gt * CIN + c0 + cA[i]);
            }
            pa[i] = v;
        }
#pragma unroll
        for (int i = 0; i < NB; ++i)
            pb[i] = *(const short8*)(W + (size_t)koB[i] * wko +
                                     (size_t)(f0 + rB[i]) * CIN + c0 + cB[i]);
    };
    auto commit = [&]() {
#pragma unroll
        for (int i = 0; i < NA; ++i)
            if (vA[i]) *(short8*)&As[rA[i]][cA[i]] = pa[i];
#pragma unroll
        for (int i = 0; i < NB; ++i)
            *(short8*)&Bs[koB[i]][rB[i]][cB[i]] = pb[i];
    };

    f32x4 acc[NMB] = {};

    issue(cbeg);
    commit();
    __syncthreads();

    for (int c0 = cbeg; c0 < cend; c0 += 64) {
        const bool nxt = (c0 + 64 < cend);
        if (nxt) issue(c0 + 64);
#pragma unroll
        for (int kk = 0; kk < 2; ++kk)
#pragma unroll
            for (int ko = 0; ko < KS; ++ko) {
                short8 bfr = *(const short8*)&Bs[ko][wv * 16 + m][kk * 32 + kq * 8];
#pragma unroll
                for (int mb = 0; mb < NMB; ++mb) {
                    short8 afr = *(const short8*)&As[mb * 16 + m + ko][kk * 32 + kq * 8];
                    acc[mb] = __builtin_amdgcn_mfma_f32_16x16x32_bf16(afr, bfr, acc[mb], 0, 0, 0);
                }
            }
        if (nxt) {
            __syncthreads();   // all fragment reads of this chunk complete
            commit();
            __syncthreads();   // staged data visible
        }
    }

    const float bs = bias[f];
    if (MODE == 2) {
        bf16* Y = (bf16*)Y0;
#pragma unroll
        for (int mb = 0; mb < NMB; ++mb)
#pragma unroll
            for (int r = 0; r < 4; ++r) {
                int t = t0 + mb * 16 + kq * 4 + r;
                float v = fmaxf(acc[mb][r] + bs, 0.f) * mask[b * Tn + t];
                Y[((size_t)b * Tn + t) * CO + f] = __float2bfloat16(v);
            }
    } else {  // MODE 4
        if (blockIdx.y < 6) {          // Q|K -> transposed, stride QKS
            bf16* Y = (bf16*)Y0;
#pragma unroll
            for (int mb = 0; mb < NMB; ++mb)
#pragma unroll
                for (int r = 0; r < 4; ++r) {
                    int t = t0 + mb * 16 + kq * 4 + r;
                    Y[((size_t)b * Tn + t) * QKS + f] = __float2bfloat16(acc[mb][r] + bs);
                }
        } else {                        // V -> bf16 NCT
            bf16* Y = (bf16*)Y1 + ((size_t)b * Cn + f - 384) * Tn;
#pragma unroll
            for (int mb = 0; mb < NMB; ++mb) {
                int t = t0 + mb * 16 + kq * 4;
                bf16 tmp[4];
#pragma unroll
                for (int r = 0; r < 4; ++r) tmp[r] = __float2bfloat16(acc[mb][r] + bs);
                *(uint2*)(Y + t) = *(uint2*)tmp;
            }
        }
    }
}

// ---------------------------------------------------------------------------
// R8: wo_ln_k at 512 threads / 8 waves (2 waves/SIMD). Waves map as
// 4 f-groups (48 ch) x 2 t-groups (16 rows); per-wave acc[3].
__global__ __launch_bounds__(512) void wo_ln_k(
        const bf16* __restrict__ Op, const float* __restrict__ Lp,
        const bf16* __restrict__ W, const float* __restrict__ bias,
        float* __restrict__ X, const float* __restrict__ G,
        const float* __restrict__ Bt, const float* __restrict__ mask,
        bf16* __restrict__ XT) {
    __shared__ bf16 As[32][72];       // combined attn out [t][c-chunk]
    __shared__ bf16 Bs[192][72];      // Wo panel [f][c-chunk]
    __shared__ float sm1[8][16];
    __shared__ float sm2[8][16];

    const int tid = threadIdx.x;
    const int wv = tid >> 6, lane = tid & 63;
    const int m = lane & 15, quad = lane >> 4;
    const int fg = wv & 3, tg = wv >> 2;
    const int b = blockIdx.x & 7;
    const int t0 = (blockIdx.x >> 3) * 32;

    const bool vA = (tid < 256);
    const int rA = tid >> 3, cA = (tid & 7) * 8;   // A: 32 rows x 8 short8
    short8 pa6[4]; float pl6[4];
    short8 pb[3];                                   // B: 1536 short8 / 512

    auto issue = [&](int c0) {
        if (vA) {
            int c = c0 + cA;
            int hh = (c >= 96) ? 1 : 0;
            int rid = (b * Hn + hh) * Tn + t0 + rA;
            int d0 = c - 96 * hh;
#pragma unroll
            for (int sp = 0; sp < 4; ++sp) {
                pa6[sp] = *(const short8*)(Op + ((size_t)sp * RN + rid) * 96 + d0);
                pl6[sp] = Lp[sp * RN + rid];
            }
        }
#pragma unroll
        for (int i = 0; i < 3; ++i) {
            int s = tid + i * 512;
            pb[i] = *(const short8*)(W + (size_t)(s >> 3) * Cn + c0 + (s & 7) * 8);
        }
    };
    auto commit = [&]() {
        if (vA) {
            float denom = pl6[0] + pl6[1] + pl6[2] + pl6[3];
            float inv = 1.f / fmaxf(denom, 1e-30f);
            bf16 tmp[8];
#pragma unroll
            for (int e = 0; e < 8; ++e) {
                float o = 0.f;
#pragma unroll
                for (int sp = 0; sp < 4; ++sp)
                    o += __bfloat162float(((const bf16*)&pa6[sp])[e]);
                tmp[e] = __float2bfloat16(o * inv);
            }
            *(short8*)&As[rA][cA] = *(const short8*)tmp;
        }
#pragma unroll
        for (int i = 0; i < 3; ++i) {
            int s = tid + i * 512;
            *(short8*)&Bs[s >> 3][(s & 7) * 8] = pb[i];
        }
    };

    f32x4 acc[3] = {};

    issue(0);
    commit();
    __syncthreads();
    for (int c0 = 0; c0 < Cn; c0 += 64) {
        const bool nxt = (c0 + 64 < Cn);
        if (nxt) issue(c0 + 64);
#pragma unroll
        for (int kk = 0; kk < 2; ++kk) {
            short8 afr = *(const short8*)&As[tg * 16 + m][kk * 32 + quad * 8];
#pragma unroll
            for (int fb = 0; fb < 3; ++fb) {
                short8 bfr = *(const short8*)&Bs[fg * 48 + fb * 16 + m][kk * 32 + quad * 8];
                acc[fb] = __builtin_amdgcn_mfma_f32_16x16x32_bf16(afr, bfr, acc[fb], 0, 0, 0);
            }
        }
        if (nxt) {
            __syncthreads();
            commit();
            __syncthreads();
        }
    }

    // bias + residual; per-t LN stats over this lane's 3 channels
    const int tq = t0 + tg * 16 + quad * 4;
    float s1[4] = {}, s2[4] = {};
#pragma unroll
    for (int fb = 0; fb < 3; ++fb) {
        const int f = fg * 48 + fb * 16 + m;
        const float bsv = bias[f];
        float4 xv = *(const float4*)(X + ((size_t)(b * Cn + f)) * Tn + tq);
        acc[fb][0] += bsv + xv.x;
        acc[fb][1] += bsv + xv.y;
        acc[fb][2] += bsv + xv.z;
        acc[fb][3] += bsv + xv.w;
#pragma unroll
        for (int r = 0; r < 4; ++r) {
            float v = acc[fb][r];
            s1[r] += v;
            s2[r] += v * v;
        }
    }
#pragma unroll
    for (int r = 0; r < 4; ++r)
#pragma unroll
        for (int mk = 1; mk < 16; mk <<= 1) {
            s1[r] += __shfl_xor(s1[r], mk);
            s2[r] += __shfl_xor(s2[r], mk);
        }
    if (m == 0) {
#pragma unroll
        for (int r = 0; r < 4; ++r) {
            sm1[wv][quad * 4 + r] = s1[r];
            sm2[wv][quad * 4 + r] = s2[r];
        }
    }
    __syncthreads();
    float mean[4], rsv[4];
    float4 mk4 = *(const float4*)(mask + b * Tn + tq);
    float mtv[4] = {mk4.x, mk4.y, mk4.z, mk4.w};
#pragma unroll
    for (int r = 0; r < 4; ++r) {
        int tt = quad * 4 + r;
        float a = sm1[tg * 4 + 0][tt] + sm1[tg * 4 + 1][tt] +
                  sm1[tg * 4 + 2][tt] + sm1[tg * 4 + 3][tt];
        float q = sm2[tg * 4 + 0][tt] + sm2[tg * 4 + 1][tt] +
                  sm2[tg * 4 + 2][tt] + sm2[tg * 4 + 3][tt];
        float mn = a / Cn;
        mean[r] = mn;
        rsv[r] = rsqrtf(q / Cn - mn * mn + 1e-5f);
    }
#pragma unroll
    for (int fb = 0; fb < 3; ++fb) {
        const int f = fg * 48 + fb * 16 + m;
        const float gv = G[f], bv = Bt[f];
        float y[4];
#pragma unroll
        for (int r = 0; r < 4; ++r)
            y[r] = (acc[fb][r] - mean[r]) * rsv[r] * gv + bv;
        float4 xo;
        xo.x = y[0]; xo.y = y[1]; xo.z = y[2]; xo.w = y[3];
        *(float4*)(X + ((size_t)(b * Cn + f)) * Tn + tq) = xo;
#pragma unroll
        for (int r = 0; r < 4; ++r)
            XT[((size_t)b * Tn + tq + r) * Cn + f] =
                __float2bfloat16(y[r] * mtv[r]);
    }
}

// ---------------------------------------------------------------------------
// R14 = R10 revert (best-known, 586 us) + entry-prefetch of the QKV weight
// chunk (T14 issue-early; loads are next-layer constants, commitQ still
// after [E1]). ffn2_ln_qkv at 768 threads / 12 waves (3 waves/SIMD).
// Waves: 6 f-groups (32 ch, acc[2]) x 2 t-groups. Phase 2 QKV: fg owns
// 96 ch (acc2[6]).
__global__ __launch_bounds__(768) void ffn2_ln_qkv(
        const bf16* __restrict__ Hc, const bf16* __restrict__ W,
        const float* __restrict__ bias, float* __restrict__ X,
        const float* __restrict__ G, const float* __restrict__ Bt,
        const float* __restrict__ mask,
        const bf16* __restrict__ Wqn, const float* __restrict__ bqn,
        bf16* __restrict__ QKT, bf16* __restrict__ Vb,
        float* __restrict__ OUT) {
    __shared__ bf16 As[34][72];        // hidden rows t0-1..t0+32, c-chunk
    __shared__ bf16 Bs[3][192][72];    // W2 panel [ko][f][c-chunk] (~83 KB)
    __shared__ float sm1[12][16];
    __shared__ float sm2[12][16];
    __shared__ bf16 Ys[32][200];       // LN2 output tile [t][c] (phase 2 A)

    const int tid = threadIdx.x;
    const int wv = tid >> 6, lane = tid & 63;
    const int m = lane & 15, quad = lane >> 4;
    const int fg = wv % 6, tg = wv / 6;      // 6 f-groups x 2 t-groups
    const int b = blockIdx.x & 7;
    const int t0 = (blockIdx.x >> 3) * 32;

    const bf16* hb = Hc + (size_t)b * Tn * FCn;

    // phase-2 QKV weight prefetch state (issued at ENTRY, hidden under
    // the whole phase-1 conv; committed only after [E1])
    short8 pbq[6];
    auto issueQ = [&](int c0) {
#pragma unroll
        for (int i = 0; i < 6; ++i) {
            int s = tid + i * 768;           // < 4608 = 576*8
            pbq[i] = *(const short8*)(Wqn + (size_t)(s >> 3) * Cn + c0 + (s & 7) * 8);
        }
    };
    if (OUT == nullptr) issueQ(0);

    const bool vA = (tid < 272);
    short8 pa, pb[6];
    auto issue = [&](int c0) {
        short8 v = {0, 0, 0, 0, 0, 0, 0, 0};
        if (vA) {
            int gt = t0 + (tid >> 3) - 1;
            if ((unsigned)gt < (unsigned)Tn)
                v = *(const short8*)(hb + (size_t)gt * FCn + c0 + (tid & 7) * 8);
        }
        pa = v;
#pragma unroll
        for (int i = 0; i < 6; ++i) {
            int s = tid + i * 768;           // < 4608 = 3*192*8
            int ko = s / 1536, rem = s - ko * 1536;
            pb[i] = *(const short8*)(W + (size_t)ko * Cn * FCn +
                                     (size_t)(rem >> 3) * FCn + c0 + (rem & 7) * 8);
        }
    };
    auto commit = [&]() {
        if (vA) *(short8*)&As[tid >> 3][(tid & 7) * 8] = pa;
#pragma unroll
        for (int i = 0; i < 6; ++i) {
            int s = tid + i * 768;
            int ko = s / 1536, rem = s - ko * 1536;
            *(short8*)&Bs[ko][rem >> 3][(rem & 7) * 8] = pb[i];
        }
    };

    f32x4 acc[2] = {};

    issue(0);
    commit();
    __syncthreads();
    for (int c0 = 0; c0 < FCn; c0 += 64) {
        const bool nxt = (c0 + 64 < FCn);
        if (nxt) issue(c0 + 64);
#pragma unroll
        for (int kk = 0; kk < 2; ++kk)
#pragma unroll
            for (int ko = 0; ko < 3; ++ko) {
                short8 afr = *(const short8*)&As[tg * 16 + m + ko][kk * 32 + quad * 8];
#pragma unroll
                for (int fb = 0; fb < 2; ++fb) {
                    short8 bfr = *(const short8*)&Bs[ko][fg * 32 + fb * 16 + m][kk * 32 + quad * 8];
                    acc[fb] = __builtin_amdgcn_mfma_f32_16x16x32_bf16(afr, bfr, acc[fb], 0, 0, 0);
                }
            }
        if (nxt) {
            __syncthreads();
            commit();
            __syncthreads();
        }
    }

    // y = (conv + bias)*mask; v = X + y; LN stats over channels
    const int tq = t0 + tg * 16 + quad * 4;
    float4 mk4 = *(const float4*)(mask + b * Tn + tq);
    float mtv[4] = {mk4.x, mk4.y, mk4.z, mk4.w};
    float s1[4] = {}, s2[4] = {};
#pragma unroll
    for (int fb = 0; fb < 2; ++fb) {
        const int f = fg * 32 + fb * 16 + m;
        const float bsv = bias[f];
        float4 xv = *(const float4*)(X + ((size_t)(b * Cn + f)) * Tn + tq);
        acc[fb][0] = xv.x + (acc[fb][0] + bsv) * mtv[0];
        acc[fb][1] = xv.y + (acc[fb][1] + bsv) * mtv[1];
        acc[fb][2] = xv.z + (acc[fb][2] + bsv) * mtv[2];
        acc[fb][3] = xv.w + (acc[fb][3] + bsv) * mtv[3];
#pragma unroll
        for (int r = 0; r < 4; ++r) {
            float v = acc[fb][r];
            s1[r] += v;
            s2[r] += v * v;
        }
    }
#pragma unroll
    for (int r = 0; r < 4; ++r)
#pragma unroll
        for (int mk = 1; mk < 16; mk <<= 1) {
            s1[r] += __shfl_xor(s1[r], mk);
            s2[r] += __shfl_xor(s2[r], mk);
        }
    if (m == 0) {
#pragma unroll
        for (int r = 0; r < 4; ++r) {
            sm1[wv][quad * 4 + r] = s1[r];
            sm2[wv][quad * 4 + r] = s2[r];
        }
    }
    __syncthreads();   // [E1] also: all Bs/As MFMA reads are now complete
    float mean[4], rsv[4];
#pragma unroll
    for (int r = 0; r < 4; ++r) {
        int tt = quad * 4 + r;
        float a = 0.f, q = 0.f;
#pragma unroll
        for (int j = 0; j < 6; ++j) {
            a += sm1[tg * 6 + j][tt];
            q += sm2[tg * 6 + j][tt];
        }
        float mn = a / Cn;
        mean[r] = mn;
        rsv[r] = rsqrtf(q / Cn - mn * mn + 1e-5f);
    }

    float y3[2][4];
#pragma unroll
    for (int fb = 0; fb < 2; ++fb) {
        const int f = fg * 32 + fb * 16 + m;
        const float gv = G[f], bv = Bt[f];
#pragma unroll
        for (int r = 0; r < 4; ++r)
            y3[fb][r] = (acc[fb][r] - mean[r]) * rsv[r] * gv + bv;
    }

    if (OUT) {      // final layer: OUT = LN(...)*mask, NCT fp32; no QKV
#pragma unroll
        for (int fb = 0; fb < 2; ++fb) {
            const int f = fg * 32 + fb * 16 + m;
            float4 xo;
            xo.x = y3[fb][0] * mtv[0]; xo.y = y3[fb][1] * mtv[1];
            xo.z = y3[fb][2] * mtv[2]; xo.w = y3[fb][3] * mtv[3];
            *(float4*)(OUT + ((size_t)(b * Cn + f)) * Tn + tq) = xo;
        }
        return;
    }

    // write X (residual stream for next layer's wo_ln_k)
#pragma unroll
    for (int fb = 0; fb < 2; ++fb) {
        const int f = fg * 32 + fb * 16 + m;
        float4 xo;
        xo.x = y3[fb][0]; xo.y = y3[fb][1]; xo.z = y3[fb][2]; xo.w = y3[fb][3];
        *(float4*)(X + ((size_t)(b * Cn + f)) * Tn + tq) = xo;
    }

    // ---- phase 2: QKV 1x1 conv for the NEXT layer ----
    bf16 (*Bq)[72] = (bf16 (*)[72])Bs;   // 576 rows x 72 — same footprint

    auto commitQ = [&]() {
#pragma unroll
        for (int i = 0; i < 6; ++i) {
            int s = tid + i * 768;
            *(short8*)&Bq[s >> 3][(s & 7) * 8] = pbq[i];
        }
    };

    // drop y (unmasked, matching old XT semantics) into the LDS A-tile
#pragma unroll
    for (int fb = 0; fb < 2; ++fb) {
        const int f = fg * 32 + fb * 16 + m;
#pragma unroll
        for (int r = 0; r < 4; ++r)
            Ys[tg * 16 + quad * 4 + r][f] = __float2bfloat16(y3[fb][r]);
    }
    commitQ();           // pbq issued at entry; safe: all Bs reads precede [E1]
    __syncthreads();     // Ys + Bq chunk 0 visible

    f32x4 acc2[6] = {};
    for (int c0 = 0; c0 < Cn; c0 += 64) {
        const bool nxt = (c0 + 64 < Cn);
        if (nxt) issueQ(c0 + 64);
#pragma unroll
        for (int kk = 0; kk < 2; ++kk) {
            short8 afr = *(const short8*)&Ys[tg * 16 + m][c0 + kk * 32 + quad * 8];
#pragma unroll
            for (int fb = 0; fb < 6; ++fb) {
                short8 bfr = *(const short8*)&Bq[fg * 96 + fb * 16 + m][kk * 32 + quad * 8];
                acc2[fb] = __builtin_amdgcn_mfma_f32_16x16x32_bf16(afr, bfr, acc2[fb], 0, 0, 0);
            }
        }
        if (nxt) {
            __syncthreads();
            commitQ();
            __syncthreads();
        }
    }

    // epilogue: QKT transposed (f<384) / Vb NCT (f>=384), bias added
#pragma unroll
    for (int fb = 0; fb < 6; ++fb) {
        const int f = fg * 96 + fb * 16 + m;
        const float bsv = bqn[f];
        if (f < 384) {
#pragma unroll
            for (int r = 0; r < 4; ++r)
                QKT[((size_t)b * Tn + tq + r) * QKS + f] =
                    __float2bfloat16(acc2[fb][r] + bsv);
        } else {
            bf16 tmp[4];
#pragma unroll
            for (int r = 0; r < 4; ++r) tmp[r] = __float2bfloat16(acc2[fb][r] + bsv);
            *(uint2*)(Vb + ((size_t)b * Cn + f - 384) * Tn + tq) = *(uint2*)tmp;
        }
    }
}

// ---------------------------------------------------------------------------
// MFMA flash attention. R8: 8 waves / QBLK=128 per block (512 threads,
// grid 512). XCD swizzle (R2), T14 async-STAGE (R2), rel-V via MFMA (R3),
// ones-MFMA rowsum + gating + setprio (R5). FIXED-MAX softmax.
// Writes UNNORMALIZED partials: Op bf16 [sp][rid][96], Lp fp32 [sp][rid].
__global__ __launch_bounds__(512) void attn_mfma(
        const bf16* __restrict__ QK, const bf16* __restrict__ V,
        const float* __restrict__ mask, const bf16* __restrict__ erkb,
        const bf16* __restrict__ ervb, bf16* __restrict__ Op,
        float* __restrict__ Lp, int layer) {
    __shared__ bf16 Ks[64][100];      // K chunk [s][d]
    __shared__ bf16 Vs[96][68];       // V chunk [d][s]
    __shared__ float rq[8][16][17];   // per-wave rel-K band: [m][dd]
    __shared__ bf16 pT[8][16][68];    // per-wave P: [m][s]
    __shared__ bf16 pdg[8][16][16];   // per-wave rel-V band: [m][dd], 9..15 zero
    // LDS total: 56064 B -> 2 blocks/CU

    const int tid = threadIdx.x, wv = tid >> 6, lane = tid & 63;
    const int col = lane & 15, quad = lane >> 4;
    // XCD-bijective swizzle (512 = 8 XCD x 64)
    const int w = (blockIdx.x & 7) * 64 + (blockIdx.x >> 3);
    const int t0 = (w & 7) * 128;
    const int yz = w >> 3;
    const int h = yz & 1;
    const int z = yz >> 1;
    const int b = z >> 2, sp = z & 3;
    const int hd = h * DKn;
    const int t0w = t0 + wv * 16;

    *(uint2*)&pdg[wv][col][quad * 4] = (uint2){0, 0};

    const bool g2 = (tid < 256);
    int rK[2], cK[2], rV[2], cV[2];
    {
        int s = tid;
        rK[0] = s / 12; cK[0] = (s % 12) * 8;   // 64 rows x 96 cols
        rV[0] = s >> 3; cV[0] = (s & 7) * 8;    // 96 rows x 64 cols
        s = tid + 512;
        rK[1] = s / 12; cK[1] = (s % 12) * 8;   // valid only if g2
        rV[1] = s >> 3; cV[1] = (s & 7) * 8;
    }
    const bf16* kbase = QK + (size_t)b * Tn * QKS + 192 + hd;
    const bf16* vbase = V + ((size_t)b * Cn + hd) * Tn;

    short8 kst[2], vst[2];
    const int sbeg = sp * (Tn / NSPLIT);
    const int send = sbeg + Tn / NSPLIT;

    kst[0] = *(const short8*)(kbase + (size_t)(sbeg + rK[0]) * QKS + cK[0]);
    vst[0] = *(const short8*)(vbase + (size_t)rV[0] * Tn + sbeg + cV[0]);
    if (g2) {
        kst[1] = *(const short8*)(kbase + (size_t)(sbeg + rK[1]) * QKS + cK[1]);
        vst[1] = *(const short8*)(vbase + (size_t)rV[1] * Tn + sbeg + cV[1]);
    }

    short8 aq[3];
    {
        const bf16* qrow = QK + ((size_t)b * Tn + t0w + col) * QKS + hd + quad * 8;
#pragma unroll
        for (int kd = 0; kd < 3; ++kd) aq[kd] = *(const short8*)(qrow + kd * 32);
    }
    {
        const bf16* erow = erkb + ((size_t)layer * 16 + col) * 96 + quad * 8;
        f32x4 R = {};
#pragma unroll
        for (int kd = 0; kd < 3; ++kd) {
            short8 be = *(const short8*)(erow + kd * 32);
            R = __builtin_amdgcn_mfma_f32_16x16x32_bf16(aq[kd], be, R, 0, 0, 0);
        }
#pragma unroll
        for (int r = 0; r < 4; ++r) rq[wv][quad * 4 + r][col] = R[r];
    }
    float mtv[4];
#pragma unroll
    for (int r = 0; r < 4; ++r) mtv[r] = mask[b * Tn + t0w + quad * 4 + r];
    const bool qok = __all(mtv[0] != 0.f && mtv[1] != 0.f &&
                           mtv[2] != 0.f && mtv[3] != 0.f);
    int okbits = 0;
    if (qok) {
#pragma unroll
        for (int ch = 0; ch < 4; ++ch) {
            int sc = b * Tn + sbeg + ch * 64 + col;
            float a0 = mask[sc], a1 = mask[sc + 16], a2 = mask[sc + 32], a3 = mask[sc + 48];
            if (__all(a0 != 0.f && a1 != 0.f && a2 != 0.f && a3 != 0.f))
                okbits |= 1 << ch;
        }
    }

    *(short8*)&Ks[rK[0]][cK[0]] = kst[0];
    *(short8*)&Vs[rV[0]][cV[0]] = vst[0];
    if (g2) {
        *(short8*)&Ks[rK[1]][cK[1]] = kst[1];
        *(short8*)&Vs[rV[1]][cV[1]] = vst[1];
    }
    __syncthreads();

    f32x4 O[6] = {};
    f32x4 Osum = {};
    short8 ones;
#pragma unroll
    for (int j = 0; j < 8; ++j) ones[j] = (short)0x3F80;   // bf16 1.0

    for (int s0 = sbeg; s0 < send; s0 += 64) {
        const bool nxt = (s0 + 64 < send);
        if (nxt) {
            kst[0] = *(const short8*)(kbase + (size_t)(s0 + 64 + rK[0]) * QKS + cK[0]);
            vst[0] = *(const short8*)(vbase + (size_t)rV[0] * Tn + s0 + 64 + cV[0]);
            if (g2) {
                kst[1] = *(const short8*)(kbase + (size_t)(s0 + 64 + rK[1]) * QKS + cK[1]);
                vst[1] = *(const short8*)(vbase + (size_t)rV[1] * Tn + s0 + 64 + cV[1]);
            }
        }

        f32x4 S[4] = {};
        __builtin_amdgcn_s_setprio(1);
#pragma unroll
        for (int nb = 0; nb < 4; ++nb)
#pragma unroll
            for (int kd = 0; kd < 3; ++kd) {
                short8 bkf = *(const short8*)&Ks[16 * nb + col][kd * 32 + quad * 8];
                S[nb] = __builtin_amdgcn_mfma_f32_16x16x32_bf16(aq[kd], bkf, S[nb], 0, 0, 0);
            }
        __builtin_amdgcn_s_setprio(0);

        const bool diag = (s0 <= t0w + 15 + WINn) && (s0 + 63 >= t0w - WINn);
        if (diag) {
#pragma unroll
            for (int nb = 0; nb < 4; ++nb) {
                const int sg = s0 + 16 * nb + col;
#pragma unroll
                for (int r = 0; r < 4; ++r) {
                    int dd = sg - (t0w + quad * 4 + r) + WINn;
                    if ((unsigned)dd <= 2u * WINn) S[nb][r] += rq[wv][quad * 4 + r][dd];
                }
            }
        }
        if (!((okbits >> ((s0 - sbeg) >> 6)) & 1)) {
#pragma unroll
            for (int nb = 0; nb < 4; ++nb) {
                const float msv = mask[b * Tn + s0 + 16 * nb + col];
#pragma unroll
                for (int r = 0; r < 4; ++r)
                    if (msv * mtv[r] == 0.f) S[nb][r] = -1e4f;
            }
        }

        if (diag) {
#pragma unroll
            for (int nb = 0; nb < 4; ++nb) {
                const int sg = s0 + 16 * nb + col;
#pragma unroll
                for (int r = 0; r < 4; ++r) {
                    bf16 pb_ = __float2bfloat16(__expf(S[nb][r]));
                    pT[wv][quad * 4 + r][16 * nb + col] = pb_;
                    int dd = sg - (t0w + quad * 4 + r) + WINn;
                    if ((unsigned)dd <= 2u * WINn) pdg[wv][quad * 4 + r][dd] = pb_;
                }
            }
        } else {
#pragma unroll
            for (int nb = 0; nb < 4; ++nb)
#pragma unroll
                for (int r = 0; r < 4; ++r)
                    pT[wv][quad * 4 + r][16 * nb + col] =
                        __float2bfloat16(__expf(S[nb][r]));
        }

        short8 aP[2];
#pragma unroll
        for (int kk = 0; kk < 2; ++kk)
            aP[kk] = *(const short8*)&pT[wv][col][kk * 32 + quad * 8];
        __builtin_amdgcn_s_setprio(1);
#pragma unroll
        for (int nd = 0; nd < 6; ++nd)
#pragma unroll
            for (int kk = 0; kk < 2; ++kk) {
                short8 bvf = *(const short8*)&Vs[16 * nd + col][kk * 32 + quad * 8];
                O[nd] = __builtin_amdgcn_mfma_f32_16x16x32_bf16(aP[kk], bvf, O[nd], 0, 0, 0);
            }
#pragma unroll
        for (int kk = 0; kk < 2; ++kk)
            Osum = __builtin_amdgcn_mfma_f32_16x16x32_bf16(aP[kk], ones, Osum, 0, 0, 0);
        __builtin_amdgcn_s_setprio(0);

        __syncthreads();
        if (nxt) {
            *(short8*)&Ks[rK[0]][cK[0]] = kst[0];
            *(short8*)&Vs[rV[0]][cV[0]] = vst[0];
            if (g2) {
                *(short8*)&Ks[rK[1]][cK[1]] = kst[1];
                *(short8*)&Vs[rV[1]][cV[1]] = vst[1];
            }
            __syncthreads();
        }
    }

    // rel-V band contribution: O += pdg(16x16, k 9..15 zero) . ERVB(k x 96)
    {
        short8 ad = {0, 0, 0, 0, 0, 0, 0, 0};
        if (quad < 2) ad = *(const short8*)&pdg[wv][col][quad * 8];
        const bf16* eb = ervb + (size_t)layer * 96 * 32 + (size_t)col * 32 + quad * 8;
#pragma unroll
        for (int nd = 0; nd < 6; ++nd) {
            short8 bd = *(const short8*)(eb + (size_t)nd * 16 * 32);
            O[nd] = __builtin_amdgcn_mfma_f32_16x16x32_bf16(ad, bd, O[nd], 0, 0, 0);
        }
    }

    // epilogue: write unnormalized partials (Lp row-sums come from Osum)
    const int rbase = (b * Hn + h) * Tn + t0w;
#pragma unroll
    for (int r = 0; r < 4; ++r) {
        const int rid = rbase + quad * 4 + r;
        bf16* dst = Op + ((size_t)sp * RN + rid) * 96 + col;
#pragma unroll
        for (int nd = 0; nd < 6; ++nd)
            dst[16 * nd] = __float2bfloat16(O[nd][r]);
        if (col == 0) Lp[sp * RN + rid] = Osum[r];
    }
}

// ---------------------------------------------------------------------------
extern "C" void kernel_launch(void* const* d_in, const int* in_sizes, int n_in,
                              void* d_out, int out_size, void* d_ws, size_t ws_size,
                              hipStream_t stream) {
    const float* x    = (const float*)d_in[0];
    const float* mask = (const float*)d_in[1];
    const float* Wq   = (const float*)d_in[2];
    const float* bq   = (const float*)d_in[3];
    const float* Wk   = (const float*)d_in[4];
    const float* bk   = (const float*)d_in[5];
    const float* Wv   = (const float*)d_in[6];
    const float* bv   = (const float*)d_in[7];
    const float* Wo   = (const float*)d_in[8];
    const float* bo   = (const float*)d_in[9];
    const float* erk  = (const float*)d_in[10];
    const float* erv  = (const float*)d_in[11];
    const float* ln1g = (const float*)d_in[12];
    const float* ln1b = (const float*)d_in[13];
    const float* w1   = (const float*)d_in[14];
    const float* b1   = (const float*)d_in[15];
    const float* w2   = (const float*)d_in[16];
    const float* b2   = (const float*)d_in[17];
    const float* ln2g = (const float*)d_in[18];
    const float* ln2b = (const float*)d_in[19];

    const size_t N = (size_t)Bn * Cn * Tn;         // 1,572,864
    const int WC = Ln * Cn * Cn;                   // 221,184
    const size_t WF = (size_t)Ln * 3 * FCn * Cn;   // 2,654,208
    const size_t WQKV = (size_t)Ln * 576 * Cn;     // 663,552
    const size_t NSCR = (size_t)Bn * Tn * FCn;     // 6,291,456 == NSPLIT*RN*96

    float* X    = (float*)d_ws;
    float* Yb   = X + N;                           // (unused since R7)
    float* bqkv = Yb + N;                          // L*576 floats
    float* Lp   = bqkv + Ln * 576;                 // NSPLIT*RN floats
    bf16* p16 = (bf16*)(Lp + (size_t)NSPLIT * RN);
    bf16* XT   = p16; p16 += N;
    bf16* QKT  = p16; p16 += (size_t)Bn * Tn * QKS;  // 2N bf16
    bf16* Vb   = p16; p16 += N;
    bf16* AT   = p16; p16 += N;      // (unused; kept for layout)
    bf16* SCR  = p16; p16 += NSCR;   // shared: attn O-partials <-> FFN hidden
    bf16* Wqkv = p16; p16 += WQKV;
    bf16* Wob  = p16; p16 += WC;
    bf16* W1t  = p16; p16 += WF;
    bf16* W2t  = p16; p16 += WF;
    bf16* ERKB = p16; p16 += Ln * 16 * 96;
    bf16* ERVB = p16; p16 += Ln * 96 * 32;
    (void)AT; (void)Yb;

    const float qscale = 0.10206207261596575f;  // 1/sqrt(96)

    // one-time transforms: single fused dispatch
    const size_t nprep = WQKV + Ln * 576 + WC + 2 * WF +
                         (size_t)Ln * 16 * 96 + (size_t)Ln * 96 * 32;
    prep_all<<<(int)((nprep + 255) / 256), 256, 0, stream>>>(
        Wq, Wk, Wv, bq, bk, bv, Wo, w1, w2, erk, erv,
        Wqkv, bqkv, Wob, W1t, W2t, ERKB, ERVB, qscale);
    cvt_in_k<<<Bn * 32, 256, 0, stream>>>(x, mask, X, XT);

    // layer 0's QKV from XT (standalone conv); layers 1..5 get QKV fused
    // into the previous layer's ffn2_ln_qkv.
    conv_mfma<1, 128, 4, 1><<<dim3(Tn / 128, 9, Bn), 256, 0, stream>>>(
        XT, Wqkv, bqkv, nullptr, QKT, Vb, Cn, 576);

    for (int l = 0; l < Ln; ++l) {
        attn_mfma<<<dim3(512), 512, 0, stream>>>(
            QKT, Vb, mask, ERKB, ERVB, SCR, Lp, l);
        // fused: split-combine + Wo conv + residual + LN1 + X/XT write
        wo_ln_k<<<256, 512, 0, stream>>>(
            SCR, Lp, Wob + (size_t)l * Cn * Cn, bo + l * Cn,
            X, ln1g + l * Cn, ln1b + l * Cn, mask, XT);
        conv_mfma<3, 128, 2, 1><<<dim3(Tn / 128, FCn / 64, Bn), 256, 0, stream>>>(
            XT, W1t + (size_t)l * 3 * FCn * Cn, b1 + l * FCn, mask, SCR, nullptr, Cn, FCn);
        // fused: FFN2 conv + mask + residual + LN2 + next layer's QKV
        const bool last = (l == Ln - 1);
        ffn2_ln_qkv<<<256, 768, 0, stream>>>(
            SCR, W2t + (size_t)l * 3 * Cn * FCn, b2 + l * Cn,
            X, ln2g + l * Cn, ln2b + l * Cn, mask,
            last ? nullptr : (Wqkv + (size_t)(l + 1) * 576 * Cn),
            last ? nullptr : (bqkv + (l + 1) * 576),
            QKT, Vb,
            last ? (float*)d_out : nullptr);
    }
}